// Round 5
// baseline (628.473 us; speedup 1.0000x reference)
//
#include <hip/hip_runtime.h>
#include <hip/hip_cooperative_groups.h>
#include <math.h>

namespace cg = cooperative_groups;

#define F 1024
#define NROWS 8192
#define NELEM (NROWS * F)

typedef unsigned short ushort_t;
typedef short bf16x8 __attribute__((ext_vector_type(8)));
typedef float f32x4 __attribute__((ext_vector_type(4)));
typedef unsigned short ushort8 __attribute__((ext_vector_type(8)));

__device__ __forceinline__ ushort_t f2bf(float f) {
  unsigned u = __float_as_uint(f);
  unsigned r = (u + 0x7fffu + ((u >> 16) & 1u)) >> 16;
  return (ushort_t)r;
}
__device__ __forceinline__ float bf2f(ushort_t b) {
  return __uint_as_float(((unsigned)b) << 16);
}

typedef const __attribute__((address_space(1))) unsigned int* gas_ptr;
typedef __attribute__((address_space(3))) unsigned int* las_ptr;
__device__ __forceinline__ void gload16(const void* g, const void* l) {
  __builtin_amdgcn_global_load_lds((gas_ptr)(unsigned long long)g,
                                   (las_ptr)(unsigned int)(unsigned long long)l,
                                   16, 0, 0);
}

// ---------------- tconv + fused sumsq ----------------
__global__ __launch_bounds__(256) void tconv_kernel(const float* __restrict__ x,
                                                    ushort_t* __restrict__ xthi,
                                                    ushort_t* __restrict__ xtlo,
                                                    float* __restrict__ partial) {
    __shared__ ushort_t th[64][68];
    __shared__ ushort_t tl[64][68];
    __shared__ float sdata[256];
    int c0 = blockIdx.x * 64;
    int r0 = blockIdx.y * 64;
    int tid = threadIdx.x;
    float ss = 0.f;
#pragma unroll
    for (int i = 0; i < 4; ++i) {
        int q = tid + 256 * i;
        int r = q >> 4;
        int cq = (q & 15) << 2;
        float4 vx = *(const float4*)&x[(size_t)(r0 + r) * 1024 + c0 + cq];
        float vv[4] = {vx.x, vx.y, vx.z, vx.w};
#pragma unroll
        for (int j = 0; j < 4; ++j) {
            ss = fmaf(vv[j], vv[j], ss);
            ushort_t h = f2bf(vv[j]);
            ushort_t l = f2bf(vv[j] - bf2f(h));
            th[r][cq + j] = h;
            tl[r][cq + j] = l;
        }
    }
    sdata[tid] = ss;
    __syncthreads();
    for (int off = 128; off > 0; off >>= 1) {
        if (tid < off) sdata[tid] += sdata[tid + off];
        __syncthreads();
    }
    if (tid == 0) partial[blockIdx.y * 16 + blockIdx.x] = sdata[0];
#pragma unroll
    for (int i = 0; i < 2; ++i) {
        int q = tid + 256 * i;
        int c = q >> 3;
        int rq = (q & 7) << 3;
        ushort8 oh, ol;
#pragma unroll
        for (int j = 0; j < 8; ++j) {
            oh[j] = th[rq + j][c];
            ol[j] = tl[rq + j][c];
        }
        *(ushort8*)&xthi[(size_t)(c0 + c) * 8192 + r0 + rq] = oh;
        *(ushort8*)&xtlo[(size_t)(c0 + c) * 8192 + r0 + rq] = ol;
    }
}

__global__ void finish_damp_kernel(const float* __restrict__ partial, float* __restrict__ scal) {
    __shared__ float sdata[256];
    int tid = threadIdx.x;
    float s = 0.f;
    for (int i = tid; i < 2048; i += 256) s += partial[i];
    sdata[tid] = s;
    __syncthreads();
    for (int off = 128; off > 0; off >>= 1) {
        if (tid < off) sdata[tid] += sdata[tid + off];
        __syncthreads();
    }
    if (tid == 0) {
        float mean = sdata[0] / (float)NELEM;
        scal[1] = 0.01f * mean;
    }
}

// ---------------- SYRK: triangle + z8, 512 threads, dbuf 64KB (2 blk/CU) ----------------
__global__ __launch_bounds__(512) void syrk_mfma_kernel(
    const ushort_t* __restrict__ XThi, const ushort_t* __restrict__ XTlo,
    float* __restrict__ P)
{
    __shared__ ushort_t smem[2 * 16384];   // 64 KB: per slot Ahi@0 Alo@4096 Bhi@8192 Blo@12288
    int id = blockIdx.x;
    int z = id & 7, t = id >> 3;
    int bi = 0;
    while ((bi + 1) * (bi + 2) / 2 <= t) ++bi;
    int bj = t - bi * (bi + 1) / 2;
    int arow0 = bi * 128, brow0 = bj * 128;
    int k0 = z * 1024;

    int tid = threadIdx.x, lane = tid & 63, w = tid >> 6;
    int wm = w >> 2, wn = w & 3;          // 2 x 4 wave grid: wave tile 64 x 32
    int lr = lane & 15, cg = lane >> 4;

    // staging indices: 512 threads cover 128 rows x 4 k-chunks per tensor
    int sr = tid >> 2, spos = tid & 3;
    int skc = (spos ^ ((sr >> 1) & 3)) << 3;
    const ushort_t* gAhi = XThi + (size_t)(arow0 + sr) * 8192 + k0 + skc;
    const ushort_t* gAlo = XTlo + (size_t)(arow0 + sr) * 8192 + k0 + skc;
    const ushort_t* gBhi = XThi + (size_t)(brow0 + sr) * 8192 + k0 + skc;
    const ushort_t* gBlo = XTlo + (size_t)(brow0 + sr) * 8192 + k0 + skc;
    int sdst = tid * 8;

    f32x4 zero4 = {0.f, 0.f, 0.f, 0.f};
    f32x4 acc[4][2];
#pragma unroll
    for (int a = 0; a < 4; ++a)
#pragma unroll
        for (int b = 0; b < 2; ++b) acc[a][b] = zero4;

#define SY_STAGE(KT)                                                               \
    {                                                                              \
        ushort_t* sb = smem + (size_t)((KT) & 1) * 16384;                          \
        int kof = (KT) << 5;                                                       \
        gload16(gAhi + kof, sb + sdst);                                            \
        gload16(gAlo + kof, sb + 4096 + sdst);                                     \
        gload16(gBhi + kof, sb + 8192 + sdst);                                     \
        gload16(gBlo + kof, sb + 12288 + sdst);                                    \
    }

#define SY_COMP(KT)                                                               \
    {                                                                              \
        const ushort_t* sb = smem + (size_t)((KT) & 1) * 16384;                    \
        int xo = (cg ^ ((lr >> 1) & 3)) << 3;                                      \
        bf16x8 ah[4], al[4], bh[2], bl[2];                                         \
        _Pragma("unroll")                                                          \
        for (int fx = 0; fx < 4; ++fx) {                                           \
            int ao = ((wm << 6) + (fx << 4) + lr) * 32 + xo;                       \
            ah[fx] = *(const bf16x8*)&sb[0 + ao];                                  \
            al[fx] = *(const bf16x8*)&sb[4096 + ao];                               \
        }                                                                          \
        _Pragma("unroll")                                                          \
        for (int fn = 0; fn < 2; ++fn) {                                           \
            int bo = ((wn << 5) + (fn << 4) + lr) * 32 + xo;                       \
            bh[fn] = *(const bf16x8*)&sb[8192 + bo];                               \
            bl[fn] = *(const bf16x8*)&sb[12288 + bo];                              \
        }                                                                          \
        _Pragma("unroll")                                                          \
        for (int fm = 0; fm < 4; ++fm)                                             \
            _Pragma("unroll")                                                      \
            for (int fn = 0; fn < 2; ++fn) {                                       \
                acc[fm][fn] = __builtin_amdgcn_mfma_f32_16x16x32_bf16(             \
                    ah[fm], bh[fn], acc[fm][fn], 0, 0, 0);                         \
                acc[fm][fn] = __builtin_amdgcn_mfma_f32_16x16x32_bf16(             \
                    ah[fm], bl[fn], acc[fm][fn], 0, 0, 0);                         \
                acc[fm][fn] = __builtin_amdgcn_mfma_f32_16x16x32_bf16(             \
                    al[fm], bh[fn], acc[fm][fn], 0, 0, 0);                         \
            }                                                                      \
    }

    SY_STAGE(0)
    for (int kt = 0; kt < 31; ++kt) {
        SY_STAGE(kt + 1)
        asm volatile("s_waitcnt vmcnt(4)" ::: "memory");
        __builtin_amdgcn_s_barrier();
        __builtin_amdgcn_sched_barrier(0);
        SY_COMP(kt)
        __builtin_amdgcn_sched_barrier(0);
        __builtin_amdgcn_s_barrier();
    }
    asm volatile("s_waitcnt vmcnt(0)" ::: "memory");
    __builtin_amdgcn_s_barrier();
    __builtin_amdgcn_sched_barrier(0);
    SY_COMP(31)

    float* Pt = P + ((size_t)(t * 8 + z) << 14);
#pragma unroll
    for (int fm = 0; fm < 4; ++fm)
#pragma unroll
        for (int fn = 0; fn < 2; ++fn)
#pragma unroll
            for (int rr = 0; rr < 4; ++rr) {
                int row = (wm << 6) + fm * 16 + cg * 4 + rr;
                int col = (wn << 5) + fn * 16 + lr;
                Pt[row * 128 + col] = acc[fm][fn][rr];
            }
}

// ---------------- fused NS GEMM phase (device fn, 256 blocks x 512 threads) ----------------
// 64x64 tile per block; bid -> (by=bid>>4, bx=bid&15). B given by rows (symmetric operand).
// slot layout (ushorts): Ahi@0 Bhi@2048 Alo@4096 Blo@6144; SLOT=8192; ring-4, prefetch-2.
template <int TERMS, int MODE>
__device__ void ns_gemm_phase(
    const ushort_t* __restrict__ Ahi, const ushort_t* __restrict__ Alo,
    const ushort_t* __restrict__ Bhi, const ushort_t* __restrict__ Blo,
    const ushort_t* __restrict__ Xchi, const ushort_t* __restrict__ Xclo,
    ushort_t* __restrict__ Ohi, ushort_t* __restrict__ Olo, float* __restrict__ Of,
    ushort_t* smem, int bid, int tid)
{
    int row0 = (bid >> 4) << 6, col0 = (bid & 15) << 6;
    int lane = tid & 63, w = tid >> 6;
    int wm = w >> 2, wn = w & 3;          // 2 x 4: wave tile 32 x 16
    int lr = lane & 15, cg = lane >> 4;

    int tt = tid & 255, which = tid >> 8;  // threads 0-255: A, 256-511: B
    int sr = tt >> 2, spos = tt & 3;
    int skc = (spos ^ ((sr >> 1) & 3)) << 3;
    const ushort_t* gHi = (which ? Bhi + (size_t)(col0 + sr) * F
                                 : Ahi + (size_t)(row0 + sr) * F) + skc;
    const ushort_t* gLo = (TERMS == 3)
        ? ((which ? Blo + (size_t)(col0 + sr) * F : Alo + (size_t)(row0 + sr) * F) + skc)
        : (const ushort_t*)nullptr;
    int sdst = which * 2048 + tt * 8;

#define NSG_STAGE(KT)                                                              \
    {                                                                              \
        ushort_t* sb = smem + (size_t)((KT) & 3) * 8192;                           \
        gload16(gHi + ((KT) << 5), sb + sdst);                                     \
        if constexpr (TERMS == 3) gload16(gLo + ((KT) << 5), sb + 4096 + sdst);    \
    }

    f32x4 acc0 = {0.f, 0.f, 0.f, 0.f}, acc1 = acc0;
    int xo = (cg ^ ((lr >> 1) & 3)) << 3;
    int aoff0 = ((wm << 5) + 0 + lr) * 32 + xo;
    int aoff1 = ((wm << 5) + 16 + lr) * 32 + xo;
    int boff = 2048 + ((wn << 4) + lr) * 32 + xo;

#define NSG_COMP(KT)                                                               \
    {                                                                              \
        const ushort_t* sb = smem + (size_t)((KT) & 3) * 8192;                     \
        bf16x8 a0 = *(const bf16x8*)&sb[aoff0];                                    \
        bf16x8 a1 = *(const bf16x8*)&sb[aoff1];                                    \
        bf16x8 b0 = *(const bf16x8*)&sb[boff];                                     \
        acc0 = __builtin_amdgcn_mfma_f32_16x16x32_bf16(a0, b0, acc0, 0, 0, 0);     \
        acc1 = __builtin_amdgcn_mfma_f32_16x16x32_bf16(a1, b0, acc1, 0, 0, 0);     \
        if constexpr (TERMS == 3) {                                                \
            bf16x8 al0 = *(const bf16x8*)&sb[4096 + aoff0];                        \
            bf16x8 al1 = *(const bf16x8*)&sb[4096 + aoff1];                        \
            bf16x8 bl0 = *(const bf16x8*)&sb[4096 + boff];                         \
            acc0 = __builtin_amdgcn_mfma_f32_16x16x32_bf16(a0, bl0, acc0, 0, 0, 0);\
            acc0 = __builtin_amdgcn_mfma_f32_16x16x32_bf16(al0, b0, acc0, 0, 0, 0);\
            acc1 = __builtin_amdgcn_mfma_f32_16x16x32_bf16(a1, bl0, acc1, 0, 0, 0);\
            acc1 = __builtin_amdgcn_mfma_f32_16x16x32_bf16(al1, b0, acc1, 0, 0, 0);\
        }                                                                          \
    }

    NSG_STAGE(0)
    NSG_STAGE(1)
    for (int kt = 0; kt < 30; ++kt) {
        NSG_STAGE(kt + 2)
        if constexpr (TERMS == 3) { asm volatile("s_waitcnt vmcnt(4)" ::: "memory"); }
        else                      { asm volatile("s_waitcnt vmcnt(2)" ::: "memory"); }
        __builtin_amdgcn_s_barrier();
        __builtin_amdgcn_sched_barrier(0);
        NSG_COMP(kt)
        __builtin_amdgcn_sched_barrier(0);
    }
    if constexpr (TERMS == 3) { asm volatile("s_waitcnt vmcnt(2)" ::: "memory"); }
    else                      { asm volatile("s_waitcnt vmcnt(1)" ::: "memory"); }
    __builtin_amdgcn_s_barrier();
    __builtin_amdgcn_sched_barrier(0);
    NSG_COMP(30)
    asm volatile("s_waitcnt vmcnt(0)" ::: "memory");
    __builtin_amdgcn_s_barrier();
    __builtin_amdgcn_sched_barrier(0);
    NSG_COMP(31)

#pragma unroll
    for (int fm = 0; fm < 2; ++fm)
#pragma unroll
        for (int rr = 0; rr < 4; ++rr) {
            float val = fm ? acc1[rr] : acc0[rr];
            int r = row0 + (wm << 5) + (fm << 4) + (cg << 2) + rr;
            int c = col0 + (wn << 4) + lr;
            size_t idx = (size_t)r * F + c;
            if constexpr (MODE == 0) {
                ushort_t h = f2bf(val);
                Ohi[idx] = h;
                Olo[idx] = f2bf(val - bf2f(h));
            } else {
                float xc = bf2f(Xchi[idx]) + bf2f(Xclo[idx]);
                val = 2.0f * xc - val;
                if constexpr (MODE == 1) {
                    ushort_t h = f2bf(val);
                    Ohi[idx] = h;
                    Olo[idx] = f2bf(val - bf2f(h));
                } else {
                    Of[idx] = val;
                }
            }
        }
}

// ---------------- fused tail: damp + reduceH + power x3 + analytic X1 + 8 GEMMs + perm ----------------
__global__ __launch_bounds__(512) void fused_tail_kernel(
    const float* __restrict__ part, float* __restrict__ scal,
    const float* __restrict__ P,
    ushort_t* __restrict__ Hhi, ushort_t* __restrict__ Hlo,
    ushort_t* __restrict__ X0hi, ushort_t* __restrict__ X0lo,
    ushort_t* __restrict__ X1hi, ushort_t* __restrict__ X1lo,
    ushort_t* __restrict__ Shi, ushort_t* __restrict__ Slo,
    float* __restrict__ v, float* __restrict__ y, float* __restrict__ out)
{
    cg::grid_group grid = cg::this_grid();
    __shared__ ushort_t smem[32768];   // 64 KB, reused across phases
    float* red = (float*)smem;
    int bid = blockIdx.x, tid = threadIdx.x;
    int lane = tid & 63, w = tid >> 6;

    // --- A: damp (block 0) ---
    if (bid == 0) {
        float s = part[tid] + part[tid + 512] + part[tid + 1024] + part[tid + 1536];
        red[tid] = s;
        __syncthreads();
        for (int off = 256; off > 0; off >>= 1) {
            if (tid < off) red[tid] += red[tid + off];
            __syncthreads();
        }
        if (tid == 0) scal[1] = 0.01f * (red[0] / (float)NELEM);
    }
    grid.sync();
    float damp = scal[1];

    // --- B: reduceH (grid-stride over 36 tiles x 16384) ---
    for (int idx = bid * 512 + tid; idx < 36 * 16384; idx += 256 * 512) {
        int tile = idx >> 14, li = idx & 16383;
        int bi = 0;
        while ((bi + 1) * (bi + 2) / 2 <= tile) ++bi;
        int bj = tile - bi * (bi + 1) / 2;
        const float* Pt = P + ((size_t)tile << 17);
        float s = 0.f;
#pragma unroll
        for (int z = 0; z < 8; ++z) s += Pt[((size_t)z << 14) + li];
        int r = li >> 7, c = li & 127;
        int gi = bi * 128 + r, gj = bj * 128 + c;
        if (gi == gj) s += damp;
        ushort_t h = f2bf(s), l = f2bf(s - bf2f(h));
        Hhi[gi * F + gj] = h;
        Hlo[gi * F + gj] = l;
        if (bi != bj) {
            Hhi[gj * F + gi] = h;
            Hlo[gj * F + gi] = l;
        }
    }
    grid.sync();

    // --- C: power iteration x3 (lam computed redundantly per block) ---
    float lam = 1.f;
    for (int it = 0; it < 3; ++it) {
        {   // matvec: row = bid*4 + (w>>1); two waves per row
            int row = bid * 4 + (w >> 1);
            int j0 = ((w & 1) << 9) + lane * 8;
            ushort8 hv = *(const ushort8*)&Hhi[(size_t)row * F + j0];
            float s = 0.f;
            if (it == 0) {
#pragma unroll
                for (int j = 0; j < 8; ++j) s += bf2f(hv[j]);
            } else {
                float4 v0 = *(const float4*)&v[j0];
                float4 v1 = *(const float4*)&v[j0 + 4];
                float vv[8] = {v0.x, v0.y, v0.z, v0.w, v1.x, v1.y, v1.z, v1.w};
#pragma unroll
                for (int j = 0; j < 8; ++j) s = fmaf(bf2f(hv[j]), vv[j], s);
            }
            for (int off = 32; off > 0; off >>= 1) s += __shfl_down(s, off);
            __syncthreads();
            if (lane == 0) red[w] = s;
            __syncthreads();
            if (tid < 4) y[bid * 4 + tid] = red[2 * tid] + red[2 * tid + 1];
        }
        grid.sync();
        {   // ||y|| in every block (identical deterministic result)
            float t0 = y[tid], t1 = y[tid + 512];
            float s = t0 * t0 + t1 * t1;
            __syncthreads();
            red[tid] = s;
            __syncthreads();
            for (int off = 256; off > 0; off >>= 1) {
                if (tid < off) red[tid] += red[tid + off];
                __syncthreads();
            }
            lam = sqrtf(red[0]);
            if (tid < 4) v[bid * 4 + tid] = y[bid * 4 + tid] / lam;
        }
        grid.sync();
    }
    float cns = 1.0f / (1.05f * lam);
    if (bid == 0 && tid == 0) { scal[2] = lam; scal[3] = cns; }

    // --- D: analytic X1 = 2c I - c^2 H  ->  X0 buffers (cur) ---
    float c2 = cns * cns;
#pragma unroll
    for (int k = 0; k < 8; ++k) {
        int idx = (bid << 12) + (k << 9) + tid;
        float hv = bf2f(Hhi[idx]) + bf2f(Hlo[idx]);
        float val = -c2 * hv + (((idx >> 10) == (idx & 1023)) ? 2.f * cns : 0.f);
        ushort_t h = f2bf(val);
        X0hi[idx] = h;
        X0lo[idx] = f2bf(val - bf2f(h));
    }
    grid.sync();

    // --- E: NS GEMM iterations (it=1 t1, it=2..4 t3; last writes fp32 out) ---
    ushort_t *ch = X0hi, *cl = X0lo, *nh = X1hi, *nl = X1lo;
    for (int it = 1; it < 5; ++it) {
        if (it == 1) {
            ns_gemm_phase<1, 0>(ch, cl, Hhi, Hlo, nullptr, nullptr, Shi, Slo, nullptr, smem, bid, tid);
            grid.sync();
            ns_gemm_phase<1, 1>(Shi, Slo, ch, cl, ch, cl, nh, nl, nullptr, smem, bid, tid);
        } else {
            ns_gemm_phase<3, 0>(ch, cl, Hhi, Hlo, nullptr, nullptr, Shi, Slo, nullptr, smem, bid, tid);
            grid.sync();
            if (it == 4)
                ns_gemm_phase<3, 2>(Shi, Slo, ch, cl, ch, cl, nullptr, nullptr, out, smem, bid, tid);
            else
                ns_gemm_phase<3, 1>(Shi, Slo, ch, cl, ch, cl, nh, nl, nullptr, smem, bid, tid);
        }
        if (it < 4) {
            grid.sync();
            ushort_t* t1p = ch; ch = nh; nh = t1p;
            ushort_t* t2p = cl; cl = nl; nl = t2p;
        }
    }

    // --- F: perm tail ---
    int g = bid * 512 + tid;
    if (g < 1024) out[(size_t)F * F + g] = (float)g;
}

// ======================= standalone fallback tail (R4 kernels) =======================
__global__ void reduceH_kernel(const float* __restrict__ P,
                               ushort_t* __restrict__ Hhi, ushort_t* __restrict__ Hlo,
                               const float* __restrict__ scal) {
    int b = blockIdx.x;
    int tile = b >> 6;
    int li = ((b & 63) << 8) + threadIdx.x;
    int bi = 0;
    while ((bi + 1) * (bi + 2) / 2 <= tile) ++bi;
    int bj = tile - bi * (bi + 1) / 2;
    const float* Pt = P + ((size_t)tile << 17);
    float s = 0.f;
#pragma unroll
    for (int z = 0; z < 8; ++z) s += Pt[((size_t)z << 14) + li];
    int r = li >> 7, c = li & 127;
    int gi = bi * 128 + r, gj = bj * 128 + c;
    if (gi == gj) s += scal[1];
    ushort_t h = f2bf(s), l = f2bf(s - bf2f(h));
    Hhi[gi * F + gj] = h;
    Hlo[gi * F + gj] = l;
    if (bi != bj) {
        Hhi[gj * F + gi] = h;
        Hlo[gj * F + gi] = l;
    }
}

__global__ void init_v_kernel(float* __restrict__ v) {
    int i = blockIdx.x * 256 + threadIdx.x;
    if (i < F) v[i] = 1.0f;
}

__global__ void matvec_bf16_kernel(const ushort_t* __restrict__ Hhi, const float* __restrict__ v,
                                   float* __restrict__ y) {
    __shared__ float sdata[256];
    int row = blockIdx.x, tid = threadIdx.x;
    float s = 0.f;
    for (int j = tid; j < F; j += 256) s = fmaf(bf2f(Hhi[row * F + j]), v[j], s);
    sdata[tid] = s;
    __syncthreads();
    for (int off = 128; off > 0; off >>= 1) {
        if (tid < off) sdata[tid] += sdata[tid + off];
        __syncthreads();
    }
    if (tid == 0) y[row] = sdata[0];
}

__global__ void normalize_kernel(const float* __restrict__ y, float* __restrict__ v,
                                 float* __restrict__ scal) {
    __shared__ float sdata[256];
    __shared__ float lam;
    int tid = threadIdx.x;
    float s = 0.f;
    for (int i = tid; i < F; i += 256) {
        float t = y[i];
        s = fmaf(t, t, s);
    }
    sdata[tid] = s;
    __syncthreads();
    for (int off = 128; off > 0; off >>= 1) {
        if (tid < off) sdata[tid] += sdata[tid + off];
        __syncthreads();
    }
    if (tid == 0) {
        lam = sqrtf(sdata[0]);
        scal[2] = lam;
        scal[3] = 1.0f / (1.05f * lam);
    }
    __syncthreads();
    float il = 1.0f / lam;
    for (int i = tid; i < F; i += 256) v[i] = y[i] * il;
}

__global__ void initX_kernel(ushort_t* __restrict__ Xchi, ushort_t* __restrict__ Xclo,
                             const float* __restrict__ scal) {
    int idx = blockIdx.x * 256 + threadIdx.x;
    int i = idx >> 10, j = idx & (F - 1);
    float val = (i == j) ? scal[3] : 0.0f;
    ushort_t h = f2bf(val);
    Xchi[idx] = h;
    Xclo[idx] = f2bf(val - bf2f(h));
}

__device__ __forceinline__ void stage64(const ushort_t* __restrict__ gp, int row0, int kk,
                                        ushort_t* sbase, int tid) {
    int r = tid >> 2, pos = tid & 3;
    int kc = (pos ^ ((r >> 1) & 3)) << 3;
    gload16(gp + (size_t)(row0 + r) * 1024 + kk + kc, sbase + (size_t)(tid >> 6 << 9));
}

template <int TERMS, int MODE>
__global__ __launch_bounds__(256) void ns_gemm_kernel(
    const ushort_t* __restrict__ Ahi, const ushort_t* __restrict__ Alo,
    const ushort_t* __restrict__ Bhi, const ushort_t* __restrict__ Blo,
    const ushort_t* __restrict__ Xchi, const ushort_t* __restrict__ Xclo,
    ushort_t* __restrict__ Ohi, ushort_t* __restrict__ Olo,
    float* __restrict__ Of)
{
    constexpr int SLOT = (TERMS == 3) ? 8192 : 4096;
    __shared__ ushort_t smem[4 * SLOT];
    int tid = threadIdx.x, lane = tid & 63, w = tid >> 6;
    int wm = w >> 1, wn = w & 1;
    int row0 = blockIdx.y * 64, col0 = blockIdx.x * 64;
    int lr = lane & 15, cg = lane >> 4;

    f32x4 zero4 = {0.f, 0.f, 0.f, 0.f};
    f32x4 acc[2][2];
#pragma unroll
    for (int a = 0; a < 2; ++a)
#pragma unroll
        for (int b = 0; b < 2; ++b) acc[a][b] = zero4;

#define NS_STAGE(KT)                                                               \
    {                                                                              \
        ushort_t* sb = smem + (size_t)((KT) & 3) * SLOT;                           \
        int kk = (KT) << 5;                                                        \
        stage64(Ahi, row0, kk, sb + 0, tid);                                       \
        stage64(Bhi, col0, kk, sb + 2048, tid);                                    \
        if constexpr (TERMS == 3) {                                                \
            stage64(Alo, row0, kk, sb + 4096, tid);                                \
            stage64(Blo, col0, kk, sb + 6144, tid);                                \
        }                                                                          \
    }

#define NS_COMPUTE(KT)                                                             \
    {                                                                              \
        const ushort_t* sb = smem + (size_t)((KT) & 3) * SLOT;                     \
        bf16x8 ah[2], bh[2], al[2], bl[2];                                         \
        _Pragma("unroll")                                                          \
        for (int fx = 0; fx < 2; ++fx) {                                           \
            int xo = (cg ^ ((lr >> 1) & 3)) << 3;                                  \
            int ao = ((wm << 5) + (fx << 4) + lr) * 32 + xo;                       \
            int bo = ((wn << 5) + (fx << 4) + lr) * 32 + xo;                       \
            ah[fx] = *(const bf16x8*)&sb[0 + ao];                                  \
            bh[fx] = *(const bf16x8*)&sb[2048 + bo];                               \
            if constexpr (TERMS == 3) {                                            \
                al[fx] = *(const bf16x8*)&sb[4096 + ao];                           \
                bl[fx] = *(const bf16x8*)&sb[6144 + bo];                           \
            }                                                                      \
        }                                                                          \
        _Pragma("unroll")                                                          \
        for (int fm = 0; fm < 2; ++fm)                                             \
            _Pragma("unroll")                                                      \
            for (int fn = 0; fn < 2; ++fn) {                                       \
                acc[fm][fn] = __builtin_amdgcn_mfma_f32_16x16x32_bf16(             \
                    ah[fm], bh[fn], acc[fm][fn], 0, 0, 0);                         \
                if constexpr (TERMS == 3) {                                        \
                    acc[fm][fn] = __builtin_amdgcn_mfma_f32_16x16x32_bf16(         \
                        ah[fm], bl[fn], acc[fm][fn], 0, 0, 0);                     \
                    acc[fm][fn] = __builtin_amdgcn_mfma_f32_16x16x32_bf16(         \
                        al[fm], bh[fn], acc[fm][fn], 0, 0, 0);                     \
                }                                                                  \
            }                                                                      \
    }

    NS_STAGE(0)
    NS_STAGE(1)
    for (int kt = 0; kt < 30; ++kt) {
        NS_STAGE(kt + 2)
        if constexpr (TERMS == 3) { asm volatile("s_waitcnt vmcnt(8)" ::: "memory"); }
        else                      { asm volatile("s_waitcnt vmcnt(4)" ::: "memory"); }
        __builtin_amdgcn_s_barrier();
        __builtin_amdgcn_sched_barrier(0);
        NS_COMPUTE(kt)
        __builtin_amdgcn_sched_barrier(0);
    }
    if constexpr (TERMS == 3) { asm volatile("s_waitcnt vmcnt(4)" ::: "memory"); }
    else                      { asm volatile("s_waitcnt vmcnt(2)" ::: "memory"); }
    __builtin_amdgcn_s_barrier();
    __builtin_amdgcn_sched_barrier(0);
    NS_COMPUTE(30)
    asm volatile("s_waitcnt vmcnt(0)" ::: "memory");
    __builtin_amdgcn_s_barrier();
    __builtin_amdgcn_sched_barrier(0);
    NS_COMPUTE(31)

#pragma unroll
    for (int fm = 0; fm < 2; ++fm)
#pragma unroll
        for (int fn = 0; fn < 2; ++fn)
#pragma unroll
            for (int rr = 0; rr < 4; ++rr) {
                int r = row0 + (wm << 5) + fm * 16 + cg * 4 + rr;
                int c = col0 + (wn << 5) + fn * 16 + lr;
                size_t idx = (size_t)r * F + c;
                float val = acc[fm][fn][rr];
                if constexpr (MODE == 0) {
                    ushort_t h = f2bf(val);
                    Ohi[idx] = h;
                    Olo[idx] = f2bf(val - bf2f(h));
                } else {
                    float xc = bf2f(Xchi[idx]) + bf2f(Xclo[idx]);
                    val = 2.0f * xc - val;
                    if constexpr (MODE == 1) {
                        ushort_t h = f2bf(val);
                        Ohi[idx] = h;
                        Olo[idx] = f2bf(val - bf2f(h));
                    } else {
                        Of[idx] = val;
                    }
                }
            }
}

__global__ void perm_kernel(float* __restrict__ out) {
    int i = blockIdx.x * 256 + threadIdx.x;
    if (i < F) out[(size_t)F * F + i] = (float)i;
}

// ======================= fp32 ultra-fallback =======================
__global__ void sumsq_partial_kernel(const float* __restrict__ x, float* __restrict__ partial) {
    __shared__ float sdata[256];
    int tid = threadIdx.x;
    int base = blockIdx.x * 4096;
    float s = 0.f;
    for (int i = tid; i < 4096; i += 256) {
        float v = x[base + i];
        s = fmaf(v, v, s);
    }
    sdata[tid] = s;
    __syncthreads();
    for (int off = 128; off > 0; off >>= 1) {
        if (tid < off) sdata[tid] += sdata[tid + off];
        __syncthreads();
    }
    if (tid == 0) partial[blockIdx.x] = sdata[0];
}

__global__ void matvec_kernel(const float* __restrict__ H, const float* __restrict__ v,
                              float* __restrict__ y) {
    __shared__ float sdata[256];
    int row = blockIdx.x, tid = threadIdx.x;
    float s = 0.f;
    for (int j = tid; j < F; j += 256) s = fmaf(H[row * F + j], v[j], s);
    sdata[tid] = s;
    __syncthreads();
    for (int off = 128; off > 0; off >>= 1) {
        if (tid < off) sdata[tid] += sdata[tid + off];
        __syncthreads();
    }
    if (tid == 0) y[row] = sdata[0];
}

__global__ __launch_bounds__(256) void syrk_kernel(const float* __restrict__ X,
                                                   float* __restrict__ H,
                                                   const float* __restrict__ scal) {
    __shared__ float LA[16][64];
    __shared__ float LB[16][64];
    int tx = threadIdx.x, ty = threadIdx.y;
    int t = ty * 16 + tx;
    int i0 = blockIdx.y * 64, j0 = blockIdx.x * 64;
    int lk = t >> 4;
    int lc = (t & 15) << 2;
    float acc[4][4] = {};
    for (int k0 = 0; k0 < NROWS; k0 += 16) {
        int r = (k0 + lk) * F;
        float4 a4 = *(const float4*)&X[r + i0 + lc];
        float4 b4 = *(const float4*)&X[r + j0 + lc];
        __syncthreads();
        *(float4*)&LA[lk][lc] = a4;
        *(float4*)&LB[lk][lc] = b4;
        __syncthreads();
#pragma unroll
        for (int kk = 0; kk < 16; ++kk) {
            float4 a = *(const float4*)&LA[kk][ty << 2];
            float4 b = *(const float4*)&LB[kk][tx << 2];
            float av[4] = {a.x, a.y, a.z, a.w};
            float bv[4] = {b.x, b.y, b.z, b.w};
#pragma unroll
            for (int rr = 0; rr < 4; ++rr)
#pragma unroll
                for (int cc = 0; cc < 4; ++cc)
                    acc[rr][cc] = fmaf(av[rr], bv[cc], acc[rr][cc]);
        }
    }
    float damp = scal[1];
#pragma unroll
    for (int rr = 0; rr < 4; ++rr) {
        int i = i0 + (ty << 2) + rr;
#pragma unroll
        for (int cc = 0; cc < 4; ++cc) {
            int j = j0 + (tx << 2) + cc;
            float v = acc[rr][cc];
            if (i == j) v += damp;
            H[i * F + j] = v;
        }
    }
}

__global__ void init_X_kernel(float* __restrict__ A, const float* __restrict__ scal) {
    int idx = blockIdx.x * 256 + threadIdx.x;
    int i = idx >> 10, j = idx & (F - 1);
    A[idx] = (i == j) ? scal[3] : 0.0f;
}

__global__ __launch_bounds__(256) void gemm_nn_kernel(const float* __restrict__ A,
                                                      const float* __restrict__ Bm,
                                                      float* __restrict__ C,
                                                      const float* __restrict__ D,
                                                      int mode) {
    __shared__ float LA[16][64];
    __shared__ float LB[16][64];
    int tx = threadIdx.x, ty = threadIdx.y;
    int t = ty * 16 + tx;
    int i0 = blockIdx.y * 64, j0 = blockIdx.x * 64;
    int aii = t >> 2;
    int akq = (t & 3) << 2;
    int bkk = t >> 4;
    int bjq = (t & 15) << 2;
    float acc[4][4] = {};
    for (int k0 = 0; k0 < F; k0 += 16) {
        float4 a4 = *(const float4*)&A[(i0 + aii) * F + k0 + akq];
        float4 b4 = *(const float4*)&Bm[(k0 + bkk) * F + j0 + bjq];
        __syncthreads();
        LA[akq + 0][aii] = a4.x;
        LA[akq + 1][aii] = a4.y;
        LA[akq + 2][aii] = a4.z;
        LA[akq + 3][aii] = a4.w;
        *(float4*)&LB[bkk][bjq] = b4;
        __syncthreads();
#pragma unroll
        for (int kk = 0; kk < 16; ++kk) {
            float4 a = *(const float4*)&LA[kk][ty << 2];
            float4 b = *(const float4*)&LB[kk][tx << 2];
            float av[4] = {a.x, a.y, a.z, a.w};
            float bv[4] = {b.x, b.y, b.z, b.w};
#pragma unroll
            for (int rr = 0; rr < 4; ++rr)
#pragma unroll
                for (int cc = 0; cc < 4; ++cc)
                    acc[rr][cc] = fmaf(av[rr], bv[cc], acc[rr][cc]);
        }
    }
#pragma unroll
    for (int rr = 0; rr < 4; ++rr) {
        int i = i0 + (ty << 2) + rr;
#pragma unroll
        for (int cc = 0; cc < 4; ++cc) {
            int j = j0 + (tx << 2) + cc;
            float v = acc[rr][cc];
            if (mode == 1) v = 2.0f * D[i * F + j] - v;
            C[i * F + j] = v;
        }
    }
}

__global__ void finalize_kernel(const float* __restrict__ A, float* __restrict__ out) {
    int idx = blockIdx.x * 256 + threadIdx.x;
    if (idx < F * F) out[idx] = A[idx];
    else if (idx < F * F + F) out[idx] = (float)(idx - F * F);
}

// ======================= launch =======================
extern "C" void kernel_launch(void* const* d_in, const int* in_sizes, int n_in,
                              void* d_out, int out_size, void* d_ws, size_t ws_size,
                              hipStream_t stream) {
    const float* x = (const float*)d_in[0];
    float* out = (float*)d_out;

    char* base = (char*)d_ws;
    size_t off = 0;
    auto alloc = [&](size_t bytes) -> char* {
        char* p = base + off;
        off += bytes;
        off = (off + 255) & ~(size_t)255;
        return p;
    };
    float*    scal = (float*)alloc(64 * 4);
    float*    part = (float*)alloc(2048 * 4);
    ushort_t* XThi = (ushort_t*)alloc((size_t)NELEM * 2);
    ushort_t* XTlo = (ushort_t*)alloc((size_t)NELEM * 2);
    ushort_t* Hhi  = (ushort_t*)alloc((size_t)F * F * 2);
    ushort_t* Hlo  = (ushort_t*)alloc((size_t)F * F * 2);
    ushort_t* X0hi = (ushort_t*)alloc((size_t)F * F * 2);
    ushort_t* X0lo = (ushort_t*)alloc((size_t)F * F * 2);
    ushort_t* X1hi = (ushort_t*)alloc((size_t)F * F * 2);
    ushort_t* X1lo = (ushort_t*)alloc((size_t)F * F * 2);
    ushort_t* Shi  = (ushort_t*)alloc((size_t)F * F * 2);
    ushort_t* Slo  = (ushort_t*)alloc((size_t)F * F * 2);
    float*    P    = (float*)alloc((size_t)36 * 8 * 16384 * 4);
    float*    v    = (float*)alloc(F * 4);
    float*    y    = (float*)alloc(F * 4);
    size_t need = off;

    if (ws_size >= need) {
        tconv_kernel<<<dim3(16, 128), 256, 0, stream>>>(x, XThi, XTlo, part);
        syrk_mfma_kernel<<<288, 512, 0, stream>>>(XThi, XTlo, P);

        void* args[] = {&part, &scal, &P, &Hhi, &Hlo, &X0hi, &X0lo,
                        &X1hi, &X1lo, &Shi, &Slo, &v, &y, &out};
        hipError_t ce = hipLaunchCooperativeKernel((const void*)fused_tail_kernel,
                                                   dim3(256), dim3(512), args, 0, stream);
        if (ce != hipSuccess) {
            // -------- multi-launch fallback tail (R4 structure) --------
            finish_damp_kernel<<<1, 256, 0, stream>>>(part, scal);
            reduceH_kernel<<<36 * 64, 256, 0, stream>>>(P, Hhi, Hlo, scal);
            init_v_kernel<<<4, 256, 0, stream>>>(v);
            for (int it = 0; it < 3; ++it) {
                matvec_bf16_kernel<<<F, 256, 0, stream>>>(Hhi, v, y);
                normalize_kernel<<<1, 256, 0, stream>>>(y, v, scal);
            }
            initX_kernel<<<(F * F) / 256, 256, 0, stream>>>(X0hi, X0lo, scal);
            ushort_t* xch = X0hi; ushort_t* xcl = X0lo;
            ushort_t* xnh = X1hi; ushort_t* xnl = X1lo;
            dim3 g(16, 16);
            for (int it = 0; it < 5; ++it) {
                bool last = (it == 4);
                if (it < 2) {
                    ns_gemm_kernel<1, 0><<<g, 256, 0, stream>>>(xch, xcl, Hhi, Hlo,
                                                                nullptr, nullptr, Shi, Slo, nullptr);
                    ns_gemm_kernel<1, 1><<<g, 256, 0, stream>>>(Shi, Slo, xch, xcl,
                                                                xch, xcl, xnh, xnl, nullptr);
                } else {
                    ns_gemm_kernel<3, 0><<<g, 256, 0, stream>>>(xch, xcl, Hhi, Hlo,
                                                                nullptr, nullptr, Shi, Slo, nullptr);
                    if (last)
                        ns_gemm_kernel<3, 2><<<g, 256, 0, stream>>>(Shi, Slo, xch, xcl,
                                                                    xch, xcl, nullptr, nullptr, out);
                    else
                        ns_gemm_kernel<3, 1><<<g, 256, 0, stream>>>(Shi, Slo, xch, xcl,
                                                                    xch, xcl, xnh, xnl, nullptr);
                }
                ushort_t* th = xch; xch = xnh; xnh = th;
                ushort_t* tl = xcl; xcl = xnl; xnl = tl;
            }
            perm_kernel<<<4, 256, 0, stream>>>(out);
        }
    } else {
        // -------- fp32 ultra-fallback --------
        float* ws = (float*)d_ws;
        float* fscal    = ws;
        float* fpartial = ws + 64;
        float* fH  = ws + 4096;
        float* fA  = fH + F * F;
        float* fB  = fA + F * F;
        float* fv  = fB + F * F;
        float* fy  = fv + F;
        float* R = out;

        sumsq_partial_kernel<<<2048, 256, 0, stream>>>(x, fpartial);
        finish_damp_kernel<<<1, 256, 0, stream>>>(fpartial, fscal);

        dim3 grid16(16, 16), blk16(16, 16);
        syrk_kernel<<<grid16, blk16, 0, stream>>>(x, fH, fscal);

        init_v_kernel<<<4, 256, 0, stream>>>(fv);
        for (int it = 0; it < 12; ++it) {
            matvec_kernel<<<F, 256, 0, stream>>>(fH, fv, fy);
            normalize_kernel<<<1, 256, 0, stream>>>(fy, fv, fscal);
        }

        init_X_kernel<<<(F * F) / 256, 256, 0, stream>>>(fA, fscal);
        float* Xc = fA;
        float* Xn = fB;
        for (int it = 0; it < 8; ++it) {
            gemm_nn_kernel<<<grid16, blk16, 0, stream>>>(fH, Xc, R, nullptr, 0);
            gemm_nn_kernel<<<grid16, blk16, 0, stream>>>(Xc, R, Xn, Xc, 1);
            float* tmp = Xc; Xc = Xn; Xn = tmp;
        }

        finalize_kernel<<<(F * F + F + 255) / 256, 256, 0, stream>>>(Xc, out);
    }
}

// Round 6
// 171.555 us; speedup vs baseline: 3.6634x; 3.6634x over previous
//
#include <hip/hip_runtime.h>
#include <math.h>

#define F 1024
#define NROWS 8192
#define NELEM (NROWS * F)

typedef unsigned short ushort_t;
typedef short bf16x8 __attribute__((ext_vector_type(8)));
typedef float f32x4 __attribute__((ext_vector_type(4)));
typedef unsigned short ushort8 __attribute__((ext_vector_type(8)));

__device__ __forceinline__ ushort_t f2bf(float f) {
  unsigned u = __float_as_uint(f);
  unsigned r = (u + 0x7fffu + ((u >> 16) & 1u)) >> 16;
  return (ushort_t)r;
}
__device__ __forceinline__ float bf2f(ushort_t b) {
  return __uint_as_float(((unsigned)b) << 16);
}

typedef const __attribute__((address_space(1))) unsigned int* gas_ptr;
typedef __attribute__((address_space(3))) unsigned int* las_ptr;
__device__ __forceinline__ void gload16(const void* g, const void* l) {
  __builtin_amdgcn_global_load_lds((gas_ptr)(unsigned long long)g,
                                   (las_ptr)(unsigned int)(unsigned long long)l,
                                   16, 0, 0);
}

// ---------------- tconv + fused sumsq ----------------
__global__ __launch_bounds__(256) void tconv_kernel(const float* __restrict__ x,
                                                    ushort_t* __restrict__ xthi,
                                                    ushort_t* __restrict__ xtlo,
                                                    float* __restrict__ partial) {
    __shared__ ushort_t th[64][68];
    __shared__ ushort_t tl[64][68];
    __shared__ float sdata[256];
    int c0 = blockIdx.x * 64;
    int r0 = blockIdx.y * 64;
    int tid = threadIdx.x;
    float ss = 0.f;
#pragma unroll
    for (int i = 0; i < 4; ++i) {
        int q = tid + 256 * i;
        int r = q >> 4;
        int cq = (q & 15) << 2;
        float4 vx = *(const float4*)&x[(size_t)(r0 + r) * 1024 + c0 + cq];
        float vv[4] = {vx.x, vx.y, vx.z, vx.w};
#pragma unroll
        for (int j = 0; j < 4; ++j) {
            ss = fmaf(vv[j], vv[j], ss);
            ushort_t h = f2bf(vv[j]);
            ushort_t l = f2bf(vv[j] - bf2f(h));
            th[r][cq + j] = h;
            tl[r][cq + j] = l;
        }
    }
    sdata[tid] = ss;
    __syncthreads();
    for (int off = 128; off > 0; off >>= 1) {
        if (tid < off) sdata[tid] += sdata[tid + off];
        __syncthreads();
    }
    if (tid == 0) partial[blockIdx.y * 16 + blockIdx.x] = sdata[0];
#pragma unroll
    for (int i = 0; i < 2; ++i) {
        int q = tid + 256 * i;
        int c = q >> 3;
        int rq = (q & 7) << 3;
        ushort8 oh, ol;
#pragma unroll
        for (int j = 0; j < 8; ++j) {
            oh[j] = th[rq + j][c];
            ol[j] = tl[rq + j][c];
        }
        *(ushort8*)&xthi[(size_t)(c0 + c) * 8192 + r0 + rq] = oh;
        *(ushort8*)&xtlo[(size_t)(c0 + c) * 8192 + r0 + rq] = ol;
    }
}

__global__ void finish_damp_kernel(const float* __restrict__ partial, float* __restrict__ scal) {
    __shared__ float sdata[256];
    int tid = threadIdx.x;
    float s = 0.f;
    for (int i = tid; i < 2048; i += 256) s += partial[i];
    sdata[tid] = s;
    __syncthreads();
    for (int off = 128; off > 0; off >>= 1) {
        if (tid < off) sdata[tid] += sdata[tid + off];
        __syncthreads();
    }
    if (tid == 0) {
        float mean = sdata[0] / (float)NELEM;
        scal[1] = 0.01f * mean;
    }
}

// ---------------- SYRK: triangle tiles, split-K <NZ>, dbuf 64KB, 256 thr (R3 body) ----------------
__device__ __forceinline__ void stage128(const ushort_t* __restrict__ gp, int row0, int kk,
                                         ushort_t* sbase, int w, int lane) {
#pragma unroll
    for (int half = 0; half < 2; ++half) {
        int s = half * 256 + (w << 6) + lane;
        int r = s >> 2, pos = s & 3;
        int kc = (pos ^ ((r >> 1) & 3)) << 3;
        gload16(gp + (size_t)(row0 + r) * 8192 + kk + kc,
                sbase + (size_t)((half << 8) + (w << 6)) * 8);
    }
}

template <int NZ>
__global__ __launch_bounds__(256, 2) void syrk_mfma_kernel(
    const ushort_t* __restrict__ XThi, const ushort_t* __restrict__ XTlo,
    float* __restrict__ P)
{
    constexpr int KCH = 8192 / NZ;      // K per z-slice
    constexpr int NKT = KCH / 32;       // K-steps
    __shared__ ushort_t smem[2][16384]; // per buf: Ahi@0 Alo@4096 Bhi@8192 Blo@12288
    int id = blockIdx.x;
    int z = id & (NZ - 1), t = id / NZ;
    int bi = 0;
    while ((bi + 1) * (bi + 2) / 2 <= t) ++bi;
    int bj = t - bi * (bi + 1) / 2;
    int arow0 = bi * 128, brow0 = bj * 128;
    int k0 = z * KCH;

    int tid = threadIdx.x, lane = tid & 63, w = tid >> 6;
    int wm = w >> 1, wn = w & 1;
    int lr = lane & 15, cg = lane >> 4;

    f32x4 zero4 = {0.f, 0.f, 0.f, 0.f};
    f32x4 acc[4][4];
#pragma unroll
    for (int a = 0; a < 4; ++a)
#pragma unroll
        for (int b = 0; b < 4; ++b) acc[a][b] = zero4;

#define SYRK_STAGE(BUF, KT)                                                        \
    {                                                                              \
        ushort_t* sb = smem[BUF];                                                  \
        int kk = k0 + ((KT) << 5);                                                 \
        stage128(XThi, arow0, kk, sb + 0, w, lane);                                \
        stage128(XTlo, arow0, kk, sb + 4096, w, lane);                             \
        stage128(XThi, brow0, kk, sb + 8192, w, lane);                             \
        stage128(XTlo, brow0, kk, sb + 12288, w, lane);                            \
    }

#define SYRK_COMPUTE(BUF)                                                          \
    {                                                                              \
        const ushort_t* sb = smem[BUF];                                            \
        bf16x8 ah[4], bh[4], al[4], bl[4];                                         \
        _Pragma("unroll")                                                          \
        for (int fx = 0; fx < 4; ++fx) {                                           \
            int xo = (cg ^ ((lr >> 1) & 3)) << 3;                                  \
            int ao = ((wm << 6) + (fx << 4) + lr) * 32 + xo;                       \
            int bo = ((wn << 6) + (fx << 4) + lr) * 32 + xo;                       \
            ah[fx] = *(const bf16x8*)&sb[0 + ao];                                  \
            al[fx] = *(const bf16x8*)&sb[4096 + ao];                               \
            bh[fx] = *(const bf16x8*)&sb[8192 + bo];                               \
            bl[fx] = *(const bf16x8*)&sb[12288 + bo];                              \
        }                                                                          \
        _Pragma("unroll")                                                          \
        for (int fm = 0; fm < 4; ++fm)                                             \
            _Pragma("unroll")                                                      \
            for (int fn = 0; fn < 4; ++fn) {                                       \
                acc[fm][fn] = __builtin_amdgcn_mfma_f32_16x16x32_bf16(             \
                    ah[fm], bh[fn], acc[fm][fn], 0, 0, 0);                         \
                acc[fm][fn] = __builtin_amdgcn_mfma_f32_16x16x32_bf16(             \
                    ah[fm], bl[fn], acc[fm][fn], 0, 0, 0);                         \
                acc[fm][fn] = __builtin_amdgcn_mfma_f32_16x16x32_bf16(             \
                    al[fm], bh[fn], acc[fm][fn], 0, 0, 0);                         \
            }                                                                      \
    }

    SYRK_STAGE(0, 0)
    for (int kt = 0; kt < NKT - 1; ++kt) {
        int buf = kt & 1;
        if (buf == 0) SYRK_STAGE(1, kt + 1) else SYRK_STAGE(0, kt + 1)
        asm volatile("s_waitcnt vmcnt(8)" ::: "memory");
        __builtin_amdgcn_s_barrier();
        __builtin_amdgcn_sched_barrier(0);
        if (buf == 0) SYRK_COMPUTE(0) else SYRK_COMPUTE(1)
        __builtin_amdgcn_sched_barrier(0);
        __builtin_amdgcn_s_barrier();
    }
    asm volatile("s_waitcnt vmcnt(0)" ::: "memory");
    __builtin_amdgcn_s_barrier();
    __builtin_amdgcn_sched_barrier(0);
    if (((NKT - 1) & 1) == 0) SYRK_COMPUTE(0) else SYRK_COMPUTE(1)

    float* Pt = P + ((size_t)(t * NZ + z) << 14);
#pragma unroll
    for (int fm = 0; fm < 4; ++fm)
#pragma unroll
        for (int fn = 0; fn < 4; ++fn)
#pragma unroll
            for (int rr = 0; rr < 4; ++rr) {
                int row = (wm << 6) + fm * 16 + cg * 4 + rr;
                int col = (wn << 6) + fn * 16 + lr;
                Pt[row * 128 + col] = acc[fm][fn][rr];
            }
}

// ---------------- reduceH<NZ>: sum z-slices, +damp, split bf16, mirror ----------------
template <int NZ>
__global__ void reduceH_kernel(const float* __restrict__ P,
                               ushort_t* __restrict__ Hhi, ushort_t* __restrict__ Hlo,
                               const float* __restrict__ scal) {
    int b = blockIdx.x;
    int tile = b >> 6;
    int li = ((b & 63) << 8) + threadIdx.x;
    int bi = 0;
    while ((bi + 1) * (bi + 2) / 2 <= tile) ++bi;
    int bj = tile - bi * (bi + 1) / 2;
    const float* Pt = P + (size_t)tile * NZ * 16384;
    float s = 0.f;
#pragma unroll
    for (int z = 0; z < NZ; ++z) s += Pt[((size_t)z << 14) + li];
    int r = li >> 7, c = li & 127;
    int gi = bi * 128 + r, gj = bj * 128 + c;
    if (gi == gj) s += scal[1];
    ushort_t h = f2bf(s), l = f2bf(s - bf2f(h));
    Hhi[gi * F + gj] = h;
    Hlo[gi * F + gj] = l;
    if (bi != bj) {
        Hhi[gj * F + gi] = h;
        Hlo[gj * F + gi] = l;
    }
}

// ---------------- power iteration (first: v implicit ones) ----------------
__global__ void matvec_bf16_kernel(const ushort_t* __restrict__ Hhi, const float* __restrict__ v,
                                   float* __restrict__ y, int first) {
    __shared__ float sdata[256];
    int row = blockIdx.x, tid = threadIdx.x;
    float s = 0.f;
    if (first) {
        for (int j = tid; j < F; j += 256) s += bf2f(Hhi[row * F + j]);
    } else {
        for (int j = tid; j < F; j += 256) s = fmaf(bf2f(Hhi[row * F + j]), v[j], s);
    }
    sdata[tid] = s;
    __syncthreads();
    for (int off = 128; off > 0; off >>= 1) {
        if (tid < off) sdata[tid] += sdata[tid + off];
        __syncthreads();
    }
    if (tid == 0) y[row] = sdata[0];
}

__global__ void normalize_kernel(const float* __restrict__ y, float* __restrict__ v,
                                 float* __restrict__ scal) {
    __shared__ float sdata[256];
    __shared__ float lam;
    int tid = threadIdx.x;
    float s = 0.f;
    for (int i = tid; i < F; i += 256) {
        float t = y[i];
        s = fmaf(t, t, s);
    }
    sdata[tid] = s;
    __syncthreads();
    for (int off = 128; off > 0; off >>= 1) {
        if (tid < off) sdata[tid] += sdata[tid + off];
        __syncthreads();
    }
    if (tid == 0) {
        lam = sqrtf(sdata[0]);
        scal[2] = lam;
        scal[3] = 1.0f / (1.05f * lam);
    }
    __syncthreads();
    float il = 1.0f / lam;
    for (int i = tid; i < F; i += 256) v[i] = y[i] * il;
}

// ---------------- analytic X1 = 2c I - c^2 H (exact first NS iterate) ----------------
__global__ void initX1_kernel(const ushort_t* __restrict__ Hhi, const ushort_t* __restrict__ Hlo,
                              ushort_t* __restrict__ Xhi, ushort_t* __restrict__ Xlo,
                              const float* __restrict__ scal) {
    int idx0 = (blockIdx.x * 256 + threadIdx.x) * 4;
    float c = scal[3];
    float c2 = c * c;
#pragma unroll
    for (int k = 0; k < 4; ++k) {
        int idx = idx0 + k;
        float hv = bf2f(Hhi[idx]) + bf2f(Hlo[idx]);
        float val = -c2 * hv + (((idx >> 10) == (idx & 1023)) ? 2.f * c : 0.f);
        ushort_t h = f2bf(val);
        Xhi[idx] = h;
        Xlo[idx] = f2bf(val - bf2f(h));
    }
}

// ---------------- NS GEMM: 64x64 tile, K=1024, ring-4 prefetch-3 (R4-measured body) ----------------
__device__ __forceinline__ void stage64(const ushort_t* __restrict__ gp, int row0, int kk,
                                        ushort_t* sbase, int tid) {
    int r = tid >> 2, pos = tid & 3;
    int kc = (pos ^ ((r >> 1) & 3)) << 3;
    gload16(gp + (size_t)(row0 + r) * 1024 + kk + kc, sbase + (size_t)(tid >> 6 << 9));
}

template <int TERMS, int MODE>
__global__ __launch_bounds__(256) void ns_gemm_kernel(
    const ushort_t* __restrict__ Ahi, const ushort_t* __restrict__ Alo,
    const ushort_t* __restrict__ Bhi, const ushort_t* __restrict__ Blo,
    const ushort_t* __restrict__ Xchi, const ushort_t* __restrict__ Xclo,
    ushort_t* __restrict__ Ohi, ushort_t* __restrict__ Olo,
    float* __restrict__ Of)
{
    constexpr int SLOT = (TERMS == 3) ? 8192 : 4096;
    __shared__ ushort_t smem[4 * SLOT];
    int tid = threadIdx.x, lane = tid & 63, w = tid >> 6;
    int wm = w >> 1, wn = w & 1;
    int row0 = blockIdx.y * 64, col0 = blockIdx.x * 64;
    int lr = lane & 15, cg = lane >> 4;

    f32x4 zero4 = {0.f, 0.f, 0.f, 0.f};
    f32x4 acc[2][2];
#pragma unroll
    for (int a = 0; a < 2; ++a)
#pragma unroll
        for (int b = 0; b < 2; ++b) acc[a][b] = zero4;

#define NS_STAGE(KT)                                                               \
    {                                                                              \
        ushort_t* sb = smem + (size_t)((KT) & 3) * SLOT;                           \
        int kk = (KT) << 5;                                                        \
        stage64(Ahi, row0, kk, sb + 0, tid);                                       \
        stage64(Bhi, col0, kk, sb + 2048, tid);                                    \
        if constexpr (TERMS == 3) {                                                \
            stage64(Alo, row0, kk, sb + 4096, tid);                                \
            stage64(Blo, col0, kk, sb + 6144, tid);                                \
        }                                                                          \
    }

#define NS_COMPUTE(KT)                                                             \
    {                                                                              \
        const ushort_t* sb = smem + (size_t)((KT) & 3) * SLOT;                     \
        bf16x8 ah[2], bh[2], al[2], bl[2];                                         \
        _Pragma("unroll")                                                          \
        for (int fx = 0; fx < 2; ++fx) {                                           \
            int xo = (cg ^ ((lr >> 1) & 3)) << 3;                                  \
            int ao = ((wm << 5) + (fx << 4) + lr) * 32 + xo;                       \
            int bo = ((wn << 5) + (fx << 4) + lr) * 32 + xo;                       \
            ah[fx] = *(const bf16x8*)&sb[0 + ao];                                  \
            bh[fx] = *(const bf16x8*)&sb[2048 + bo];                               \
            if constexpr (TERMS == 3) {                                            \
                al[fx] = *(const bf16x8*)&sb[4096 + ao];                           \
                bl[fx] = *(const bf16x8*)&sb[6144 + bo];                           \
            }                                                                      \
        }                                                                          \
        _Pragma("unroll")                                                          \
        for (int fm = 0; fm < 2; ++fm)                                             \
            _Pragma("unroll")                                                      \
            for (int fn = 0; fn < 2; ++fn) {                                       \
                acc[fm][fn] = __builtin_amdgcn_mfma_f32_16x16x32_bf16(             \
                    ah[fm], bh[fn], acc[fm][fn], 0, 0, 0);                         \
                if constexpr (TERMS == 3) {                                        \
                    acc[fm][fn] = __builtin_amdgcn_mfma_f32_16x16x32_bf16(         \
                        ah[fm], bl[fn], acc[fm][fn], 0, 0, 0);                     \
                    acc[fm][fn] = __builtin_amdgcn_mfma_f32_16x16x32_bf16(         \
                        al[fm], bh[fn], acc[fm][fn], 0, 0, 0);                     \
                }                                                                  \
            }                                                                      \
    }

    NS_STAGE(0)
    NS_STAGE(1)
    for (int kt = 0; kt < 30; ++kt) {
        NS_STAGE(kt + 2)
        if constexpr (TERMS == 3) { asm volatile("s_waitcnt vmcnt(8)" ::: "memory"); }
        else                      { asm volatile("s_waitcnt vmcnt(4)" ::: "memory"); }
        __builtin_amdgcn_s_barrier();
        __builtin_amdgcn_sched_barrier(0);
        NS_COMPUTE(kt)
        __builtin_amdgcn_sched_barrier(0);
    }
    if constexpr (TERMS == 3) { asm volatile("s_waitcnt vmcnt(4)" ::: "memory"); }
    else                      { asm volatile("s_waitcnt vmcnt(2)" ::: "memory"); }
    __builtin_amdgcn_s_barrier();
    __builtin_amdgcn_sched_barrier(0);
    NS_COMPUTE(30)
    asm volatile("s_waitcnt vmcnt(0)" ::: "memory");
    __builtin_amdgcn_s_barrier();
    __builtin_amdgcn_sched_barrier(0);
    NS_COMPUTE(31)

#pragma unroll
    for (int fm = 0; fm < 2; ++fm)
#pragma unroll
        for (int fn = 0; fn < 2; ++fn)
#pragma unroll
            for (int rr = 0; rr < 4; ++rr) {
                int r = row0 + (wm << 5) + fm * 16 + cg * 4 + rr;
                int c = col0 + (wn << 5) + fn * 16 + lr;
                size_t idx = (size_t)r * F + c;
                float val = acc[fm][fn][rr];
                if constexpr (MODE == 0) {
                    ushort_t h = f2bf(val);
                    Ohi[idx] = h;
                    Olo[idx] = f2bf(val - bf2f(h));
                } else {
                    float xc = bf2f(Xchi[idx]) + bf2f(Xclo[idx]);
                    val = 2.0f * xc - val;
                    if constexpr (MODE == 1) {
                        ushort_t h = f2bf(val);
                        Ohi[idx] = h;
                        Olo[idx] = f2bf(val - bf2f(h));
                    } else {
                        Of[idx] = val;
                    }
                }
            }
    if constexpr (MODE == 2) {
        // fused perm tail (one block)
        if (blockIdx.x == 0 && blockIdx.y == 0) {
            int i0 = tid * 4;
#pragma unroll
            for (int k = 0; k < 4; ++k)
                Of[(size_t)F * F + i0 + k] = (float)(i0 + k);
        }
    }
}

// ======================= fp32 ultra-fallback =======================
__global__ void sumsq_partial_kernel(const float* __restrict__ x, float* __restrict__ partial) {
    __shared__ float sdata[256];
    int tid = threadIdx.x;
    int base = blockIdx.x * 4096;
    float s = 0.f;
    for (int i = tid; i < 4096; i += 256) {
        float v = x[base + i];
        s = fmaf(v, v, s);
    }
    sdata[tid] = s;
    __syncthreads();
    for (int off = 128; off > 0; off >>= 1) {
        if (tid < off) sdata[tid] += sdata[tid + off];
        __syncthreads();
    }
    if (tid == 0) partial[blockIdx.x] = sdata[0];
}

__global__ void init_v_kernel(float* __restrict__ v) {
    int i = blockIdx.x * 256 + threadIdx.x;
    if (i < F) v[i] = 1.0f;
}

__global__ void matvec_kernel(const float* __restrict__ H, const float* __restrict__ v,
                              float* __restrict__ y) {
    __shared__ float sdata[256];
    int row = blockIdx.x, tid = threadIdx.x;
    float s = 0.f;
    for (int j = tid; j < F; j += 256) s = fmaf(H[row * F + j], v[j], s);
    sdata[tid] = s;
    __syncthreads();
    for (int off = 128; off > 0; off >>= 1) {
        if (tid < off) sdata[tid] += sdata[tid + off];
        __syncthreads();
    }
    if (tid == 0) y[row] = sdata[0];
}

__global__ __launch_bounds__(256) void syrk_kernel(const float* __restrict__ X,
                                                   float* __restrict__ H,
                                                   const float* __restrict__ scal) {
    __shared__ float LA[16][64];
    __shared__ float LB[16][64];
    int tx = threadIdx.x, ty = threadIdx.y;
    int t = ty * 16 + tx;
    int i0 = blockIdx.y * 64, j0 = blockIdx.x * 64;
    int lk = t >> 4;
    int lc = (t & 15) << 2;
    float acc[4][4] = {};
    for (int k0 = 0; k0 < NROWS; k0 += 16) {
        int r = (k0 + lk) * F;
        float4 a4 = *(const float4*)&X[r + i0 + lc];
        float4 b4 = *(const float4*)&X[r + j0 + lc];
        __syncthreads();
        *(float4*)&LA[lk][lc] = a4;
        *(float4*)&LB[lk][lc] = b4;
        __syncthreads();
#pragma unroll
        for (int kk = 0; kk < 16; ++kk) {
            float4 a = *(const float4*)&LA[kk][ty << 2];
            float4 b = *(const float4*)&LB[kk][tx << 2];
            float av[4] = {a.x, a.y, a.z, a.w};
            float bv[4] = {b.x, b.y, b.z, b.w};
#pragma unroll
            for (int rr = 0; rr < 4; ++rr)
#pragma unroll
                for (int cc = 0; cc < 4; ++cc)
                    acc[rr][cc] = fmaf(av[rr], bv[cc], acc[rr][cc]);
        }
    }
    float damp = scal[1];
#pragma unroll
    for (int rr = 0; rr < 4; ++rr) {
        int i = i0 + (ty << 2) + rr;
#pragma unroll
        for (int cc = 0; cc < 4; ++cc) {
            int j = j0 + (tx << 2) + cc;
            float v = acc[rr][cc];
            if (i == j) v += damp;
            H[i * F + j] = v;
        }
    }
}

__global__ void init_X_kernel(float* __restrict__ A, const float* __restrict__ scal) {
    int idx = blockIdx.x * 256 + threadIdx.x;
    int i = idx >> 10, j = idx & (F - 1);
    A[idx] = (i == j) ? scal[3] : 0.0f;
}

__global__ __launch_bounds__(256) void gemm_nn_kernel(const float* __restrict__ A,
                                                      const float* __restrict__ Bm,
                                                      float* __restrict__ C,
                                                      const float* __restrict__ D,
                                                      int mode) {
    __shared__ float LA[16][64];
    __shared__ float LB[16][64];
    int tx = threadIdx.x, ty = threadIdx.y;
    int t = ty * 16 + tx;
    int i0 = blockIdx.y * 64, j0 = blockIdx.x * 64;
    int aii = t >> 2;
    int akq = (t & 3) << 2;
    int bkk = t >> 4;
    int bjq = (t & 15) << 2;
    float acc[4][4] = {};
    for (int k0 = 0; k0 < F; k0 += 16) {
        float4 a4 = *(const float4*)&A[(i0 + aii) * F + k0 + akq];
        float4 b4 = *(const float4*)&Bm[(k0 + bkk) * F + j0 + bjq];
        __syncthreads();
        LA[akq + 0][aii] = a4.x;
        LA[akq + 1][aii] = a4.y;
        LA[akq + 2][aii] = a4.z;
        LA[akq + 3][aii] = a4.w;
        *(float4*)&LB[bkk][bjq] = b4;
        __syncthreads();
#pragma unroll
        for (int kk = 0; kk < 16; ++kk) {
            float4 a = *(const float4*)&LA[kk][ty << 2];
            float4 b = *(const float4*)&LB[kk][tx << 2];
            float av[4] = {a.x, a.y, a.z, a.w};
            float bv[4] = {b.x, b.y, b.z, b.w};
#pragma unroll
            for (int rr = 0; rr < 4; ++rr)
#pragma unroll
                for (int cc = 0; cc < 4; ++cc)
                    acc[rr][cc] = fmaf(av[rr], bv[cc], acc[rr][cc]);
        }
    }
#pragma unroll
    for (int rr = 0; rr < 4; ++rr) {
        int i = i0 + (ty << 2) + rr;
#pragma unroll
        for (int cc = 0; cc < 4; ++cc) {
            int j = j0 + (tx << 2) + cc;
            float v = acc[rr][cc];
            if (mode == 1) v = 2.0f * D[i * F + j] - v;
            C[i * F + j] = v;
        }
    }
}

__global__ void finalize_kernel(const float* __restrict__ A, float* __restrict__ out) {
    int idx = blockIdx.x * 256 + threadIdx.x;
    if (idx < F * F) out[idx] = A[idx];
    else if (idx < F * F + F) out[idx] = (float)(idx - F * F);
}

// ======================= launch =======================
extern "C" void kernel_launch(void* const* d_in, const int* in_sizes, int n_in,
                              void* d_out, int out_size, void* d_ws, size_t ws_size,
                              hipStream_t stream) {
    const float* x = (const float*)d_in[0];
    float* out = (float*)d_out;

    char* base = (char*)d_ws;
    size_t off = 0;
    auto alloc = [&](size_t bytes) -> char* {
        char* p = base + off;
        off += bytes;
        off = (off + 255) & ~(size_t)255;
        return p;
    };
    float*    scal = (float*)alloc(64 * 4);
    float*    part = (float*)alloc(2048 * 4);
    ushort_t* XThi = (ushort_t*)alloc((size_t)NELEM * 2);
    ushort_t* XTlo = (ushort_t*)alloc((size_t)NELEM * 2);
    ushort_t* Hhi  = (ushort_t*)alloc((size_t)F * F * 2);
    ushort_t* Hlo  = (ushort_t*)alloc((size_t)F * F * 2);
    ushort_t* X0hi = (ushort_t*)alloc((size_t)F * F * 2);
    ushort_t* X0lo = (ushort_t*)alloc((size_t)F * F * 2);
    ushort_t* X1hi = (ushort_t*)alloc((size_t)F * F * 2);
    ushort_t* X1lo = (ushort_t*)alloc((size_t)F * F * 2);
    ushort_t* Shi  = (ushort_t*)alloc((size_t)F * F * 2);
    ushort_t* Slo  = (ushort_t*)alloc((size_t)F * F * 2);
    float*    v    = (float*)alloc(F * 4);
    float*    y    = (float*)alloc(F * 4);
    float*    P    = (float*)alloc(0);   // placed last, sized below
    size_t base_off = off;
    size_t need8  = base_off + (size_t)36 * 8  * 16384 * 4;
    size_t need16 = base_off + (size_t)36 * 16 * 16384 * 4;

    if (ws_size >= need8) {
        // ======== MFMA path ========
        tconv_kernel<<<dim3(16, 128), 256, 0, stream>>>(x, XThi, XTlo, part);
        finish_damp_kernel<<<1, 256, 0, stream>>>(part, scal);

        if (ws_size >= need16) {
            syrk_mfma_kernel<16><<<36 * 16, 256, 0, stream>>>(XThi, XTlo, P);
            reduceH_kernel<16><<<36 * 64, 256, 0, stream>>>(P, Hhi, Hlo, scal);
        } else {
            syrk_mfma_kernel<8><<<36 * 8, 256, 0, stream>>>(XThi, XTlo, P);
            reduceH_kernel<8><<<36 * 64, 256, 0, stream>>>(P, Hhi, Hlo, scal);
        }

        // power iteration x2 (first pass uses implicit ones vector)
        matvec_bf16_kernel<<<F, 256, 0, stream>>>(Hhi, v, y, 1);
        normalize_kernel<<<1, 256, 0, stream>>>(y, v, scal);
        matvec_bf16_kernel<<<F, 256, 0, stream>>>(Hhi, v, y, 0);
        normalize_kernel<<<1, 256, 0, stream>>>(y, v, scal);

        // analytic X1 (exact first NS iterate)
        initX1_kernel<<<1024, 256, 0, stream>>>(Hhi, Hlo, X0hi, X0lo, scal);

        // 4 NS iterations: [t1, t3, t3, t3]; last writes fp32 out + perm
        ushort_t* xch = X0hi; ushort_t* xcl = X0lo;
        ushort_t* xnh = X1hi; ushort_t* xnl = X1lo;
        dim3 g(16, 16);
        for (int it = 0; it < 4; ++it) {
            bool last = (it == 3);
            if (it < 1) {
                ns_gemm_kernel<1, 0><<<g, 256, 0, stream>>>(xch, xcl, Hhi, Hlo,
                                                            nullptr, nullptr, Shi, Slo, nullptr);
                ns_gemm_kernel<1, 1><<<g, 256, 0, stream>>>(Shi, Slo, xch, xcl,
                                                            xch, xcl, xnh, xnl, nullptr);
            } else {
                ns_gemm_kernel<3, 0><<<g, 256, 0, stream>>>(xch, xcl, Hhi, Hlo,
                                                            nullptr, nullptr, Shi, Slo, nullptr);
                if (last)
                    ns_gemm_kernel<3, 2><<<g, 256, 0, stream>>>(Shi, Slo, xch, xcl,
                                                                xch, xcl, nullptr, nullptr, out);
                else
                    ns_gemm_kernel<3, 1><<<g, 256, 0, stream>>>(Shi, Slo, xch, xcl,
                                                                xch, xcl, xnh, xnl, nullptr);
            }
            ushort_t* th = xch; xch = xnh; xnh = th;
            ushort_t* tl = xcl; xcl = xnl; xnl = tl;
        }
    } else {
        // -------- fp32 ultra-fallback --------
        float* ws = (float*)d_ws;
        float* fscal    = ws;
        float* fpartial = ws + 64;
        float* fH  = ws + 4096;
        float* fA  = fH + F * F;
        float* fB  = fA + F * F;
        float* fv  = fB + F * F;
        float* fy  = fv + F;
        float* R = out;

        sumsq_partial_kernel<<<2048, 256, 0, stream>>>(x, fpartial);
        finish_damp_kernel<<<1, 256, 0, stream>>>(fpartial, fscal);

        dim3 grid16(16, 16), blk16(16, 16);
        syrk_kernel<<<grid16, blk16, 0, stream>>>(x, fH, fscal);

        init_v_kernel<<<4, 256, 0, stream>>>(fv);
        for (int it = 0; it < 12; ++it) {
            matvec_kernel<<<F, 256, 0, stream>>>(fH, fv, fy);
            normalize_kernel<<<1, 256, 0, stream>>>(fy, fv, fscal);
        }

        init_X_kernel<<<(F * F) / 256, 256, 0, stream>>>(fA, fscal);
        float* Xc = fA;
        float* Xn = fB;
        for (int it = 0; it < 8; ++it) {
            gemm_nn_kernel<<<grid16, blk16, 0, stream>>>(fH, Xc, R, nullptr, 0);
            gemm_nn_kernel<<<grid16, blk16, 0, stream>>>(Xc, R, Xn, Xc, 1);
            float* tmp = Xc; Xc = Xn; Xn = tmp;
        }

        finalize_kernel<<<(F * F + F + 255) / 256, 256, 0, stream>>>(Xc, out);
    }
}

// Round 7
// 163.436 us; speedup vs baseline: 3.8454x; 1.0497x over previous
//
#include <hip/hip_runtime.h>
#include <math.h>

#define F 1024
#define NROWS 8192
#define NELEM (NROWS * F)

typedef unsigned short ushort_t;
typedef short bf16x8 __attribute__((ext_vector_type(8)));
typedef float f32x4 __attribute__((ext_vector_type(4)));
typedef unsigned short ushort8 __attribute__((ext_vector_type(8)));

__device__ __forceinline__ ushort_t f2bf(float f) {
  unsigned u = __float_as_uint(f);
  unsigned r = (u + 0x7fffu + ((u >> 16) & 1u)) >> 16;
  return (ushort_t)r;
}
__device__ __forceinline__ float bf2f(ushort_t b) {
  return __uint_as_float(((unsigned)b) << 16);
}

typedef const __attribute__((address_space(1))) unsigned int* gas_ptr;
typedef __attribute__((address_space(3))) unsigned int* las_ptr;
__device__ __forceinline__ void gload16(const void* g, const void* l) {
  __builtin_amdgcn_global_load_lds((gas_ptr)(unsigned long long)g,
                                   (las_ptr)(unsigned int)(unsigned long long)l,
                                   16, 0, 0);
}

// ---------------- tconv + fused sumsq ----------------
__global__ __launch_bounds__(256) void tconv_kernel(const float* __restrict__ x,
                                                    ushort_t* __restrict__ xthi,
                                                    ushort_t* __restrict__ xtlo,
                                                    float* __restrict__ partial) {
    __shared__ ushort_t th[64][68];
    __shared__ ushort_t tl[64][68];
    __shared__ float sdata[256];
    int c0 = blockIdx.x * 64;
    int r0 = blockIdx.y * 64;
    int tid = threadIdx.x;
    float ss = 0.f;
#pragma unroll
    for (int i = 0; i < 4; ++i) {
        int q = tid + 256 * i;
        int r = q >> 4;
        int cq = (q & 15) << 2;
        float4 vx = *(const float4*)&x[(size_t)(r0 + r) * 1024 + c0 + cq];
        float vv[4] = {vx.x, vx.y, vx.z, vx.w};
#pragma unroll
        for (int j = 0; j < 4; ++j) {
            ss = fmaf(vv[j], vv[j], ss);
            ushort_t h = f2bf(vv[j]);
            ushort_t l = f2bf(vv[j] - bf2f(h));
            th[r][cq + j] = h;
            tl[r][cq + j] = l;
        }
    }
    sdata[tid] = ss;
    __syncthreads();
    for (int off = 128; off > 0; off >>= 1) {
        if (tid < off) sdata[tid] += sdata[tid + off];
        __syncthreads();
    }
    if (tid == 0) partial[blockIdx.y * 16 + blockIdx.x] = sdata[0];
#pragma unroll
    for (int i = 0; i < 2; ++i) {
        int q = tid + 256 * i;
        int c = q >> 3;
        int rq = (q & 7) << 3;
        ushort8 oh, ol;
#pragma unroll
        for (int j = 0; j < 8; ++j) {
            oh[j] = th[rq + j][c];
            ol[j] = tl[rq + j][c];
        }
        *(ushort8*)&xthi[(size_t)(c0 + c) * 8192 + r0 + rq] = oh;
        *(ushort8*)&xtlo[(size_t)(c0 + c) * 8192 + r0 + rq] = ol;
    }
}

// ---------------- SYRK: triangle + z8, dbuf 64KB, diag half-staging ----------------
__device__ __forceinline__ void stage128(const ushort_t* __restrict__ gp, int row0, int kk,
                                         ushort_t* sbase, int w, int lane) {
#pragma unroll
    for (int half = 0; half < 2; ++half) {
        int s = half * 256 + (w << 6) + lane;
        int r = s >> 2, pos = s & 3;
        int kc = (pos ^ ((r >> 1) & 3)) << 3;
        gload16(gp + (size_t)(row0 + r) * 8192 + kk + kc,
                sbase + (size_t)((half << 8) + (w << 6)) * 8);
    }
}

__global__ __launch_bounds__(256, 2) void syrk_mfma_kernel(
    const ushort_t* __restrict__ XThi, const ushort_t* __restrict__ XTlo,
    float* __restrict__ P)
{
    __shared__ ushort_t smem[2][16384]; // per buf: Ahi@0 Alo@4096 Bhi@8192 Blo@12288
    int id = blockIdx.x;
    int z = id & 7, t = id >> 3;
    int bi = 0;
    while ((bi + 1) * (bi + 2) / 2 <= t) ++bi;
    int bj = t - bi * (bi + 1) / 2;
    int arow0 = bi * 128, brow0 = bj * 128;
    int k0 = z * 1024;

    int tid = threadIdx.x, lane = tid & 63, w = tid >> 6;
    int wm = w >> 1, wn = w & 1;
    int lr = lane & 15, cg = lane >> 4;

    f32x4 zero4 = {0.f, 0.f, 0.f, 0.f};
    f32x4 acc[4][4];
#pragma unroll
    for (int a = 0; a < 4; ++a)
#pragma unroll
        for (int b = 0; b < 4; ++b) acc[a][b] = zero4;

#define SY_STAGE_F(BUF, KT)                                                        \
    {                                                                              \
        ushort_t* sb = smem[BUF];                                                  \
        int kk = k0 + ((KT) << 5);                                                 \
        stage128(XThi, arow0, kk, sb + 0, w, lane);                                \
        stage128(XTlo, arow0, kk, sb + 4096, w, lane);                             \
        stage128(XThi, brow0, kk, sb + 8192, w, lane);                             \
        stage128(XTlo, brow0, kk, sb + 12288, w, lane);                            \
    }

#define SY_STAGE_D(BUF, KT)                                                        \
    {                                                                              \
        ushort_t* sb = smem[BUF];                                                  \
        int kk = k0 + ((KT) << 5);                                                 \
        stage128(XThi, arow0, kk, sb + 0, w, lane);                                \
        stage128(XTlo, arow0, kk, sb + 4096, w, lane);                             \
    }

#define SY_COMP(BUF, BH, BL)                                                       \
    {                                                                              \
        const ushort_t* sb = smem[BUF];                                            \
        bf16x8 ah[4], bh[4], al[4], bl[4];                                         \
        _Pragma("unroll")                                                          \
        for (int fx = 0; fx < 4; ++fx) {                                           \
            int xo = (cg ^ ((lr >> 1) & 3)) << 3;                                  \
            int ao = ((wm << 6) + (fx << 4) + lr) * 32 + xo;                       \
            int bo = ((wn << 6) + (fx << 4) + lr) * 32 + xo;                       \
            ah[fx] = *(const bf16x8*)&sb[0 + ao];                                  \
            al[fx] = *(const bf16x8*)&sb[4096 + ao];                               \
            bh[fx] = *(const bf16x8*)&sb[(BH) + bo];                               \
            bl[fx] = *(const bf16x8*)&sb[(BL) + bo];                               \
        }                                                                          \
        _Pragma("unroll")                                                          \
        for (int fm = 0; fm < 4; ++fm)                                             \
            _Pragma("unroll")                                                      \
            for (int fn = 0; fn < 4; ++fn) {                                       \
                acc[fm][fn] = __builtin_amdgcn_mfma_f32_16x16x32_bf16(             \
                    ah[fm], bh[fn], acc[fm][fn], 0, 0, 0);                         \
                acc[fm][fn] = __builtin_amdgcn_mfma_f32_16x16x32_bf16(             \
                    ah[fm], bl[fn], acc[fm][fn], 0, 0, 0);                         \
                acc[fm][fn] = __builtin_amdgcn_mfma_f32_16x16x32_bf16(             \
                    al[fm], bh[fn], acc[fm][fn], 0, 0, 0);                         \
            }                                                                      \
    }

    if (bi != bj) {
        SY_STAGE_F(0, 0)
        for (int kt = 0; kt < 31; ++kt) {
            int buf = kt & 1;
            if (buf == 0) SY_STAGE_F(1, kt + 1) else SY_STAGE_F(0, kt + 1)
            asm volatile("s_waitcnt vmcnt(8)" ::: "memory");
            __builtin_amdgcn_s_barrier();
            __builtin_amdgcn_sched_barrier(0);
            if (buf == 0) SY_COMP(0, 8192, 12288) else SY_COMP(1, 8192, 12288)
            __builtin_amdgcn_sched_barrier(0);
            __builtin_amdgcn_s_barrier();
        }
        asm volatile("s_waitcnt vmcnt(0)" ::: "memory");
        __builtin_amdgcn_s_barrier();
        __builtin_amdgcn_sched_barrier(0);
        SY_COMP(1, 8192, 12288)
    } else {
        // diagonal tile: B panel == A panel, stage only A, alias reads
        SY_STAGE_D(0, 0)
        for (int kt = 0; kt < 31; ++kt) {
            int buf = kt & 1;
            if (buf == 0) SY_STAGE_D(1, kt + 1) else SY_STAGE_D(0, kt + 1)
            asm volatile("s_waitcnt vmcnt(4)" ::: "memory");
            __builtin_amdgcn_s_barrier();
            __builtin_amdgcn_sched_barrier(0);
            if (buf == 0) SY_COMP(0, 0, 4096) else SY_COMP(1, 0, 4096)
            __builtin_amdgcn_sched_barrier(0);
            __builtin_amdgcn_s_barrier();
        }
        asm volatile("s_waitcnt vmcnt(0)" ::: "memory");
        __builtin_amdgcn_s_barrier();
        __builtin_amdgcn_sched_barrier(0);
        SY_COMP(1, 0, 4096)
    }

    float* Pt = P + ((size_t)(t * 8 + z) << 14);
#pragma unroll
    for (int fm = 0; fm < 4; ++fm)
#pragma unroll
        for (int fn = 0; fn < 4; ++fn)
#pragma unroll
            for (int rr = 0; rr < 4; ++rr) {
                int row = (wm << 6) + fm * 16 + cg * 4 + rr;
                int col = (wn << 6) + fn * 16 + lr;
                Pt[row * 128 + col] = acc[fm][fn][rr];
            }
}

// ---------------- reduceH: fused damp-reduce + z8 sum + split + mirror ----------------
__global__ void reduceH_kernel(const float* __restrict__ P, const float* __restrict__ part,
                               ushort_t* __restrict__ Hhi, ushort_t* __restrict__ Hlo) {
    __shared__ float red[256];
    int tid = threadIdx.x;
    // redundant per-block damp reduction (deterministic, identical everywhere)
    float s0 = 0.f;
    for (int i = tid; i < 2048; i += 256) s0 += part[i];
    red[tid] = s0;
    __syncthreads();
    for (int off = 128; off > 0; off >>= 1) {
        if (tid < off) red[tid] += red[tid + off];
        __syncthreads();
    }
    float damp = 0.01f * (red[0] / (float)NELEM);

    int b = blockIdx.x;
    int tile = b >> 6;
    int li = ((b & 63) << 8) + tid;
    int bi = 0;
    while ((bi + 1) * (bi + 2) / 2 <= tile) ++bi;
    int bj = tile - bi * (bi + 1) / 2;
    const float* Pt = P + ((size_t)tile << 17);
    float s = 0.f;
#pragma unroll
    for (int z = 0; z < 8; ++z) s += Pt[((size_t)z << 14) + li];
    int r = li >> 7, c = li & 127;
    int gi = bi * 128 + r, gj = bj * 128 + c;
    if (gi == gj) s += damp;
    ushort_t h = f2bf(s), l = f2bf(s - bf2f(h));
    Hhi[gi * F + gj] = h;
    Hlo[gi * F + gj] = l;
    if (bi != bj) {
        Hhi[gj * F + gi] = h;
        Hlo[gj * F + gi] = l;
    }
}

// ---------------- single matvec: y = H * ones (bf16 H) ----------------
__global__ void matvec_bf16_kernel(const ushort_t* __restrict__ Hhi, const float* __restrict__ v,
                                   float* __restrict__ y, int first) {
    __shared__ float sdata[256];
    int row = blockIdx.x, tid = threadIdx.x;
    float s = 0.f;
    if (first) {
        for (int j = tid; j < F; j += 256) s += bf2f(Hhi[row * F + j]);
    } else {
        for (int j = tid; j < F; j += 256) s = fmaf(bf2f(Hhi[row * F + j]), v[j], s);
    }
    sdata[tid] = s;
    __syncthreads();
    for (int off = 128; off > 0; off >>= 1) {
        if (tid < off) sdata[tid] += sdata[tid + off];
        __syncthreads();
    }
    if (tid == 0) y[row] = sdata[0];
}

// ---------------- initX1: lam = ||y||/32 (per-block), c = 1/(1.15 lam), X1 = 2cI - c^2 H ----------------
__global__ void initX1_kernel(const ushort_t* __restrict__ Hhi, const ushort_t* __restrict__ Hlo,
                              ushort_t* __restrict__ Xhi, ushort_t* __restrict__ Xlo,
                              const float* __restrict__ y, float* __restrict__ scal) {
    __shared__ float red[256];
    int tid = threadIdx.x;
    float4 a = ((const float4*)y)[tid];
    float s = a.x * a.x + a.y * a.y + a.z * a.z + a.w * a.w;
    red[tid] = s;
    __syncthreads();
    for (int off = 128; off > 0; off >>= 1) {
        if (tid < off) red[tid] += red[tid + off];
        __syncthreads();
    }
    float lam = sqrtf(red[0]) * (1.0f / 32.0f);   // ||H*1|| / ||1||
    float c = 1.0f / (1.15f * lam);
    if (blockIdx.x == 0 && tid == 0) { scal[2] = lam; scal[3] = c; }
    float c2 = c * c;
    int idx0 = (blockIdx.x * 256 + tid) * 4;
#pragma unroll
    for (int k = 0; k < 4; ++k) {
        int idx = idx0 + k;
        float hv = bf2f(Hhi[idx]) + bf2f(Hlo[idx]);
        float val = -c2 * hv + (((idx >> 10) == (idx & 1023)) ? 2.f * c : 0.f);
        ushort_t h = f2bf(val);
        Xhi[idx] = h;
        Xlo[idx] = f2bf(val - bf2f(h));
    }
}

// ---------------- NS GEMM: 64x64 tile, K=1024, ring-4 prefetch-2 (R4/R6-measured body) ----------------
__device__ __forceinline__ void stage64(const ushort_t* __restrict__ gp, int row0, int kk,
                                        ushort_t* sbase, int tid) {
    int r = tid >> 2, pos = tid & 3;
    int kc = (pos ^ ((r >> 1) & 3)) << 3;
    gload16(gp + (size_t)(row0 + r) * 1024 + kk + kc, sbase + (size_t)(tid >> 6 << 9));
}

template <int TERMS, int MODE>
__global__ __launch_bounds__(256) void ns_gemm_kernel(
    const ushort_t* __restrict__ Ahi, const ushort_t* __restrict__ Alo,
    const ushort_t* __restrict__ Bhi, const ushort_t* __restrict__ Blo,
    const ushort_t* __restrict__ Xchi, const ushort_t* __restrict__ Xclo,
    ushort_t* __restrict__ Ohi, ushort_t* __restrict__ Olo,
    float* __restrict__ Of)
{
    constexpr int SLOT = (TERMS == 3) ? 8192 : 4096;
    __shared__ ushort_t smem[4 * SLOT];
    int tid = threadIdx.x, lane = tid & 63, w = tid >> 6;
    int wm = w >> 1, wn = w & 1;
    int row0 = blockIdx.y * 64, col0 = blockIdx.x * 64;
    int lr = lane & 15, cg = lane >> 4;

    f32x4 zero4 = {0.f, 0.f, 0.f, 0.f};
    f32x4 acc[2][2];
#pragma unroll
    for (int a = 0; a < 2; ++a)
#pragma unroll
        for (int b = 0; b < 2; ++b) acc[a][b] = zero4;

#define NS_STAGE(KT)                                                               \
    {                                                                              \
        ushort_t* sb = smem + (size_t)((KT) & 3) * SLOT;                           \
        int kk = (KT) << 5;                                                        \
        stage64(Ahi, row0, kk, sb + 0, tid);                                       \
        stage64(Bhi, col0, kk, sb + 2048, tid);                                    \
        if constexpr (TERMS == 3) {                                                \
            stage64(Alo, row0, kk, sb + 4096, tid);                                \
            stage64(Blo, col0, kk, sb + 6144, tid);                                \
        }                                                                          \
    }

#define NS_COMPUTE(KT)                                                             \
    {                                                                              \
        const ushort_t* sb = smem + (size_t)((KT) & 3) * SLOT;                     \
        bf16x8 ah[2], bh[2], al[2], bl[2];                                         \
        _Pragma("unroll")                                                          \
        for (int fx = 0; fx < 2; ++fx) {                                           \
            int xo = (cg ^ ((lr >> 1) & 3)) << 3;                                  \
            int ao = ((wm << 5) + (fx << 4) + lr) * 32 + xo;                       \
            int bo = ((wn << 5) + (fx << 4) + lr) * 32 + xo;                       \
            ah[fx] = *(const bf16x8*)&sb[0 + ao];                                  \
            bh[fx] = *(const bf16x8*)&sb[2048 + bo];                               \
            if constexpr (TERMS == 3) {                                            \
                al[fx] = *(const bf16x8*)&sb[4096 + ao];                           \
                bl[fx] = *(const bf16x8*)&sb[6144 + bo];                           \
            }                                                                      \
        }                                                                          \
        _Pragma("unroll")                                                          \
        for (int fm = 0; fm < 2; ++fm)                                             \
            _Pragma("unroll")                                                      \
            for (int fn = 0; fn < 2; ++fn) {                                       \
                acc[fm][fn] = __builtin_amdgcn_mfma_f32_16x16x32_bf16(             \
                    ah[fm], bh[fn], acc[fm][fn], 0, 0, 0);                         \
                if constexpr (TERMS == 3) {                                        \
                    acc[fm][fn] = __builtin_amdgcn_mfma_f32_16x16x32_bf16(         \
                        ah[fm], bl[fn], acc[fm][fn], 0, 0, 0);                     \
                    acc[fm][fn] = __builtin_amdgcn_mfma_f32_16x16x32_bf16(         \
                        al[fm], bh[fn], acc[fm][fn], 0, 0, 0);                     \
                }                                                                  \
            }                                                                      \
    }

    NS_STAGE(0)
    NS_STAGE(1)
    for (int kt = 0; kt < 30; ++kt) {
        NS_STAGE(kt + 2)
        if constexpr (TERMS == 3) { asm volatile("s_waitcnt vmcnt(8)" ::: "memory"); }
        else                      { asm volatile("s_waitcnt vmcnt(4)" ::: "memory"); }
        __builtin_amdgcn_s_barrier();
        __builtin_amdgcn_sched_barrier(0);
        NS_COMPUTE(kt)
        __builtin_amdgcn_sched_barrier(0);
    }
    if constexpr (TERMS == 3) { asm volatile("s_waitcnt vmcnt(4)" ::: "memory"); }
    else                      { asm volatile("s_waitcnt vmcnt(2)" ::: "memory"); }
    __builtin_amdgcn_s_barrier();
    __builtin_amdgcn_sched_barrier(0);
    NS_COMPUTE(30)
    asm volatile("s_waitcnt vmcnt(0)" ::: "memory");
    __builtin_amdgcn_s_barrier();
    __builtin_amdgcn_sched_barrier(0);
    NS_COMPUTE(31)

#pragma unroll
    for (int fm = 0; fm < 2; ++fm)
#pragma unroll
        for (int fn = 0; fn < 2; ++fn)
#pragma unroll
            for (int rr = 0; rr < 4; ++rr) {
                int r = row0 + (wm << 5) + fm * 16 + cg * 4 + rr;
                int c = col0 + (wn << 5) + fn * 16 + lr;
                size_t idx = (size_t)r * F + c;
                float val = acc[fm][fn][rr];
                if constexpr (MODE == 0) {
                    ushort_t h = f2bf(val);
                    Ohi[idx] = h;
                    Olo[idx] = f2bf(val - bf2f(h));
                } else {
                    float xc = bf2f(Xchi[idx]) + bf2f(Xclo[idx]);
                    val = 2.0f * xc - val;
                    if constexpr (MODE == 1) {
                        ushort_t h = f2bf(val);
                        Ohi[idx] = h;
                        Olo[idx] = f2bf(val - bf2f(h));
                    } else {
                        Of[idx] = val;
                    }
                }
            }
    if constexpr (MODE == 2) {
        if (blockIdx.x == 0 && blockIdx.y == 0) {
            int i0 = tid * 4;
#pragma unroll
            for (int k = 0; k < 4; ++k)
                Of[(size_t)F * F + i0 + k] = (float)(i0 + k);
        }
    }
}

// ======================= fp32 ultra-fallback =======================
__global__ void sumsq_partial_kernel(const float* __restrict__ x, float* __restrict__ partial) {
    __shared__ float sdata[256];
    int tid = threadIdx.x;
    int base = blockIdx.x * 4096;
    float s = 0.f;
    for (int i = tid; i < 4096; i += 256) {
        float v = x[base + i];
        s = fmaf(v, v, s);
    }
    sdata[tid] = s;
    __syncthreads();
    for (int off = 128; off > 0; off >>= 1) {
        if (tid < off) sdata[tid] += sdata[tid + off];
        __syncthreads();
    }
    if (tid == 0) partial[blockIdx.x] = sdata[0];
}

__global__ void finish_damp_kernel(const float* __restrict__ partial, float* __restrict__ scal) {
    __shared__ float sdata[256];
    int tid = threadIdx.x;
    float s = 0.f;
    for (int i = tid; i < 2048; i += 256) s += partial[i];
    sdata[tid] = s;
    __syncthreads();
    for (int off = 128; off > 0; off >>= 1) {
        if (tid < off) sdata[tid] += sdata[tid + off];
        __syncthreads();
    }
    if (tid == 0) {
        float mean = sdata[0] / (float)NELEM;
        scal[1] = 0.01f * mean;
    }
}

__global__ void init_v_kernel(float* __restrict__ v) {
    int i = blockIdx.x * 256 + threadIdx.x;
    if (i < F) v[i] = 1.0f;
}

__global__ void matvec_kernel(const float* __restrict__ H, const float* __restrict__ v,
                              float* __restrict__ y) {
    __shared__ float sdata[256];
    int row = blockIdx.x, tid = threadIdx.x;
    float s = 0.f;
    for (int j = tid; j < F; j += 256) s = fmaf(H[row * F + j], v[j], s);
    sdata[tid] = s;
    __syncthreads();
    for (int off = 128; off > 0; off >>= 1) {
        if (tid < off) sdata[tid] += sdata[tid + off];
        __syncthreads();
    }
    if (tid == 0) y[row] = sdata[0];
}

__global__ void normalize_kernel(const float* __restrict__ y, float* __restrict__ v,
                                 float* __restrict__ scal) {
    __shared__ float sdata[256];
    __shared__ float lam;
    int tid = threadIdx.x;
    float s = 0.f;
    for (int i = tid; i < F; i += 256) {
        float t = y[i];
        s = fmaf(t, t, s);
    }
    sdata[tid] = s;
    __syncthreads();
    for (int off = 128; off > 0; off >>= 1) {
        if (tid < off) sdata[tid] += sdata[tid + off];
        __syncthreads();
    }
    if (tid == 0) {
        lam = sqrtf(sdata[0]);
        scal[2] = lam;
        scal[3] = 1.0f / (1.05f * lam);
    }
    __syncthreads();
    float il = 1.0f / lam;
    for (int i = tid; i < F; i += 256) v[i] = y[i] * il;
}

__global__ __launch_bounds__(256) void syrk_kernel(const float* __restrict__ X,
                                                   float* __restrict__ H,
                                                   const float* __restrict__ scal) {
    __shared__ float LA[16][64];
    __shared__ float LB[16][64];
    int tx = threadIdx.x, ty = threadIdx.y;
    int t = ty * 16 + tx;
    int i0 = blockIdx.y * 64, j0 = blockIdx.x * 64;
    int lk = t >> 4;
    int lc = (t & 15) << 2;
    float acc[4][4] = {};
    for (int k0 = 0; k0 < NROWS; k0 += 16) {
        int r = (k0 + lk) * F;
        float4 a4 = *(const float4*)&X[r + i0 + lc];
        float4 b4 = *(const float4*)&X[r + j0 + lc];
        __syncthreads();
        *(float4*)&LA[lk][lc] = a4;
        *(float4*)&LB[lk][lc] = b4;
        __syncthreads();
#pragma unroll
        for (int kk = 0; kk < 16; ++kk) {
            float4 a = *(const float4*)&LA[kk][ty << 2];
            float4 b = *(const float4*)&LB[kk][tx << 2];
            float av[4] = {a.x, a.y, a.z, a.w};
            float bv[4] = {b.x, b.y, b.z, b.w};
#pragma unroll
            for (int rr = 0; rr < 4; ++rr)
#pragma unroll
                for (int cc = 0; cc < 4; ++cc)
                    acc[rr][cc] = fmaf(av[rr], bv[cc], acc[rr][cc]);
        }
    }
    float damp = scal[1];
#pragma unroll
    for (int rr = 0; rr < 4; ++rr) {
        int i = i0 + (ty << 2) + rr;
#pragma unroll
        for (int cc = 0; cc < 4; ++cc) {
            int j = j0 + (tx << 2) + cc;
            float v = acc[rr][cc];
            if (i == j) v += damp;
            H[i * F + j] = v;
        }
    }
}

__global__ void init_X_kernel(float* __restrict__ A, const float* __restrict__ scal) {
    int idx = blockIdx.x * 256 + threadIdx.x;
    int i = idx >> 10, j = idx & (F - 1);
    A[idx] = (i == j) ? scal[3] : 0.0f;
}

__global__ __launch_bounds__(256) void gemm_nn_kernel(const float* __restrict__ A,
                                                      const float* __restrict__ Bm,
                                                      float* __restrict__ C,
                                                      const float* __restrict__ D,
                                                      int mode) {
    __shared__ float LA[16][64];
    __shared__ float LB[16][64];
    int tx = threadIdx.x, ty = threadIdx.y;
    int t = ty * 16 + tx;
    int i0 = blockIdx.y * 64, j0 = blockIdx.x * 64;
    int aii = t >> 2;
    int akq = (t & 3) << 2;
    int bkk = t >> 4;
    int bjq = (t & 15) << 2;
    float acc[4][4] = {};
    for (int k0 = 0; k0 < F; k0 += 16) {
        float4 a4 = *(const float4*)&A[(i0 + aii) * F + k0 + akq];
        float4 b4 = *(const float4*)&Bm[(k0 + bkk) * F + j0 + bjq];
        __syncthreads();
        LA[akq + 0][aii] = a4.x;
        LA[akq + 1][aii] = a4.y;
        LA[akq + 2][aii] = a4.z;
        LA[akq + 3][aii] = a4.w;
        *(float4*)&LB[bkk][bjq] = b4;
        __syncthreads();
#pragma unroll
        for (int kk = 0; kk < 16; ++kk) {
            float4 a = *(const float4*)&LA[kk][ty << 2];
            float4 b = *(const float4*)&LB[kk][tx << 2];
            float av[4] = {a.x, a.y, a.z, a.w};
            float bv[4] = {b.x, b.y, b.z, b.w};
#pragma unroll
            for (int rr = 0; rr < 4; ++rr)
#pragma unroll
                for (int cc = 0; cc < 4; ++cc)
                    acc[rr][cc] = fmaf(av[rr], bv[cc], acc[rr][cc]);
        }
    }
#pragma unroll
    for (int rr = 0; rr < 4; ++rr) {
        int i = i0 + (ty << 2) + rr;
#pragma unroll
        for (int cc = 0; cc < 4; ++cc) {
            int j = j0 + (tx << 2) + cc;
            float v = acc[rr][cc];
            if (mode == 1) v = 2.0f * D[i * F + j] - v;
            C[i * F + j] = v;
        }
    }
}

__global__ void finalize_kernel(const float* __restrict__ A, float* __restrict__ out) {
    int idx = blockIdx.x * 256 + threadIdx.x;
    if (idx < F * F) out[idx] = A[idx];
    else if (idx < F * F + F) out[idx] = (float)(idx - F * F);
}

// ======================= launch =======================
extern "C" void kernel_launch(void* const* d_in, const int* in_sizes, int n_in,
                              void* d_out, int out_size, void* d_ws, size_t ws_size,
                              hipStream_t stream) {
    const float* x = (const float*)d_in[0];
    float* out = (float*)d_out;

    char* base = (char*)d_ws;
    size_t off = 0;
    auto alloc = [&](size_t bytes) -> char* {
        char* p = base + off;
        off += bytes;
        off = (off + 255) & ~(size_t)255;
        return p;
    };
    float*    scal = (float*)alloc(64 * 4);
    float*    part = (float*)alloc(2048 * 4);
    ushort_t* XThi = (ushort_t*)alloc((size_t)NELEM * 2);
    ushort_t* XTlo = (ushort_t*)alloc((size_t)NELEM * 2);
    ushort_t* Hhi  = (ushort_t*)alloc((size_t)F * F * 2);
    ushort_t* Hlo  = (ushort_t*)alloc((size_t)F * F * 2);
    ushort_t* X0hi = (ushort_t*)alloc((size_t)F * F * 2);
    ushort_t* X0lo = (ushort_t*)alloc((size_t)F * F * 2);
    ushort_t* X1hi = (ushort_t*)alloc((size_t)F * F * 2);
    ushort_t* X1lo = (ushort_t*)alloc((size_t)F * F * 2);
    ushort_t* Shi  = (ushort_t*)alloc((size_t)F * F * 2);
    ushort_t* Slo  = (ushort_t*)alloc((size_t)F * F * 2);
    float*    v    = (float*)alloc(F * 4);
    float*    y    = (float*)alloc(F * 4);
    float*    P    = (float*)alloc((size_t)36 * 8 * 16384 * 4);
    size_t need = off;

    if (ws_size >= need) {
        // ======== MFMA path (13 launches) ========
        tconv_kernel<<<dim3(16, 128), 256, 0, stream>>>(x, XThi, XTlo, part);

        syrk_mfma_kernel<<<288, 256, 0, stream>>>(XThi, XTlo, P);
        reduceH_kernel<<<36 * 64, 256, 0, stream>>>(P, part, Hhi, Hlo);

        // single matvec: y = H * ones  -> lambda estimate sqrt(mean lambda^2)
        matvec_bf16_kernel<<<F, 256, 0, stream>>>(Hhi, v, y, 1);

        // X1 = 2cI - c^2 H  (exact first NS iterate), c = 1/(1.15*||y||/32)
        initX1_kernel<<<1024, 256, 0, stream>>>(Hhi, Hlo, X0hi, X0lo, y, scal);

        // 4 NS iterations: [t1, t3, t3, t3]; last writes fp32 out + perm
        ushort_t* xch = X0hi; ushort_t* xcl = X0lo;
        ushort_t* xnh = X1hi; ushort_t* xnl = X1lo;
        dim3 g(16, 16);
        for (int it = 0; it < 4; ++it) {
            bool last = (it == 3);
            if (it < 1) {
                ns_gemm_kernel<1, 0><<<g, 256, 0, stream>>>(xch, xcl, Hhi, Hlo,
                                                            nullptr, nullptr, Shi, Slo, nullptr);
                ns_gemm_kernel<1, 1><<<g, 256, 0, stream>>>(Shi, Slo, xch, xcl,
                                                            xch, xcl, xnh, xnl, nullptr);
            } else {
                ns_gemm_kernel<3, 0><<<g, 256, 0, stream>>>(xch, xcl, Hhi, Hlo,
                                                            nullptr, nullptr, Shi, Slo, nullptr);
                if (last)
                    ns_gemm_kernel<3, 2><<<g, 256, 0, stream>>>(Shi, Slo, xch, xcl,
                                                                xch, xcl, nullptr, nullptr, out);
                else
                    ns_gemm_kernel<3, 1><<<g, 256, 0, stream>>>(Shi, Slo, xch, xcl,
                                                                xch, xcl, xnh, xnl, nullptr);
            }
            ushort_t* th = xch; xch = xnh; xnh = th;
            ushort_t* tl = xcl; xcl = xnl; xnl = tl;
        }
    } else {
        // -------- fp32 ultra-fallback --------
        float* ws = (float*)d_ws;
        float* fscal    = ws;
        float* fpartial = ws + 64;
        float* fH  = ws + 4096;
        float* fA  = fH + F * F;
        float* fB  = fA + F * F;
        float* fv  = fB + F * F;
        float* fy  = fv + F;
        float* R = out;

        sumsq_partial_kernel<<<2048, 256, 0, stream>>>(x, fpartial);
        finish_damp_kernel<<<1, 256, 0, stream>>>(fpartial, fscal);

        dim3 grid16(16, 16), blk16(16, 16);
        syrk_kernel<<<grid16, blk16, 0, stream>>>(x, fH, fscal);

        init_v_kernel<<<4, 256, 0, stream>>>(fv);
        for (int it = 0; it < 12; ++it) {
            matvec_kernel<<<F, 256, 0, stream>>>(fH, fv, fy);
            normalize_kernel<<<1, 256, 0, stream>>>(fy, fv, fscal);
        }

        init_X_kernel<<<(F * F) / 256, 256, 0, stream>>>(fA, fscal);
        float* Xc = fA;
        float* Xn = fB;
        for (int it = 0; it < 8; ++it) {
            gemm_nn_kernel<<<grid16, blk16, 0, stream>>>(fH, Xc, R, nullptr, 0);
            gemm_nn_kernel<<<grid16, blk16, 0, stream>>>(Xc, R, Xn, Xc, 1);
            float* tmp = Xc; Xc = Xn; Xn = tmp;
        }

        finalize_kernel<<<(F * F + F + 255) / 256, 256, 0, stream>>>(Xc, out);
    }
}